// Round 8
// baseline (238.599 us; speedup 1.0000x reference)
//
#include <hip/hip_runtime.h>
#include <math.h>

// GraphSAGE (mean) + GCN + softmax. Activations RNE-bf16, weights split
// hi/lo bf16, f32 accumulate. MFMA operand-swapped (A=weights, B=activations)
// so D gives each lane 4 consecutive FEATURES of one node -> packed epilogues.
// N=100000, E=625000, D_IN=D_H=128, D_OUT=64 (derived from in_sizes).

#define DIN 128
#define DH  128
#define DOUT 64
#define U_STR 264   // 256 + 8 pad (ushort): row 528B, 16B-aligned
#define H_STR 136   // 128 + 8 pad (ushort): row 272B, 8B-aligned

typedef __attribute__((ext_vector_type(8))) short short8v;            // 8 bf16
typedef __attribute__((ext_vector_type(4))) float float4v;            // MFMA acc
typedef __attribute__((ext_vector_type(8))) unsigned short ushort8v;  // 8 bf16
typedef __attribute__((ext_vector_type(4))) unsigned short ushort4v;  // 4 bf16

// split f32 -> bf16 hi (truncate) + bf16 lo (residual, truncate)
__device__ __forceinline__ void splitf(float a, unsigned short& hi, unsigned short& lo) {
    unsigned ai = __float_as_uint(a);
    hi = (unsigned short)(ai >> 16);
    float r = a - __uint_as_float(ai & 0xffff0000u);
    lo = (unsigned short)(__float_as_uint(r) >> 16);
}

// f32 -> bf16 round-to-nearest-even
__device__ __forceinline__ unsigned short f2bf_rne(float f) {
    unsigned u = __float_as_uint(f);
    return (unsigned short)((u + 0x7fffu + ((u >> 16) & 1u)) >> 16);
}

__device__ __forceinline__ float bf2f(unsigned short u) {
    return __uint_as_float(((unsigned)u) << 16);
}

// ---------------- edge-index dtype detection (int64 vs int32) --------------
__global__ void detect_idx_kernel(const void* ei, int twoE, int* flag) {
    __shared__ int ok;
    if (threadIdx.x == 0) ok = 1;
    __syncthreads();
    const int* p = (const int*)ei;
    for (int i = threadIdx.x; i < 512; i += blockDim.x) {
        long long pos = 1 + ((long long)i * (long long)(twoE - 2)) / 512;
        pos |= 1;
        if (pos < twoE && p[pos] != 0) ok = 0;
    }
    __syncthreads();
    if (threadIdx.x == 0) *flag = ok;  // 1 => int64, 0 => int32
}

__device__ __forceinline__ void load_edge(const void* ei, int e, int E, int is64,
                                          int& s, int& d) {
    if (is64) {
        const long long* p = (const long long*)ei;
        s = (int)p[e];
        d = (int)p[E + e];
    } else {
        const int* p = (const int*)ei;
        s = p[e];
        d = p[E + e];
    }
}

// ---------------- prep: weight split + x -> bf16 ---------------------------
__global__ void prep_all(const float* __restrict__ Wl, const float* __restrict__ Wr,
                         const float* __restrict__ Wg,
                         unsigned short* __restrict__ WcH, unsigned short* __restrict__ WcL,
                         unsigned short* __restrict__ WgH, unsigned short* __restrict__ WgL,
                         const float* __restrict__ x, unsigned short* __restrict__ xbf,
                         size_t xElems) {
    size_t idx = (size_t)blockIdx.x * 256 + threadIdx.x;
    if (idx < 128 * 256) {
        int o = (int)(idx >> 8), k = (int)(idx & 255);
        float v = (k < 128) ? Wl[o * 128 + k] : Wr[o * 128 + (k - 128)];
        unsigned short h, l;
        splitf(v, h, l);
        WcH[idx] = h; WcL[idx] = l;
    } else if (idx < 128 * 256 + 64 * 128) {
        size_t j = idx - 128 * 256;
        unsigned short h, l;
        splitf(Wg[j], h, l);
        WgH[j] = h; WgL[j] = l;
    } else {
        size_t j = (idx - (128 * 256 + 64 * 128)) * 4;
        if (j < xElems) {
            float4 v = *(const float4*)(x + j);
            ushort4v o;
            o[0] = f2bf_rne(v.x);
            o[1] = f2bf_rne(v.y);
            o[2] = f2bf_rne(v.z);
            o[3] = f2bf_rne(v.w);
            *(ushort4v*)(xbf + j) = o;
        }
    }
}

// ---------------- CSR build -----------------------------------------------
__global__ void count_deg(const void* __restrict__ ei, const int* __restrict__ flag,
                          int* __restrict__ deg, int E) {
    int e = blockIdx.x * 256 + threadIdx.x;
    if (e >= E) return;
    int s, d;
    load_edge(ei, e, E, *flag, s, d);
    atomicAdd(&deg[d], 1);
}

__global__ void scan_partial(const int* __restrict__ deg, int* __restrict__ partial, int N) {
    int base = blockIdx.x * 1024;
    int t = threadIdx.x;
    int s = 0;
    for (int i = t; i < 1024; i += 256) {
        int g = base + i;
        if (g < N) s += deg[g];
    }
    __shared__ int sh[256];
    sh[t] = s;
    __syncthreads();
    for (int off = 128; off; off >>= 1) {
        if (t < off) sh[t] += sh[t + off];
        __syncthreads();
    }
    if (t == 0) partial[blockIdx.x] = sh[0];
}

__global__ void scan_offsets(int* partial, int nblk, int* rowptr, int N, int E) {
    if (threadIdx.x == 0 && blockIdx.x == 0) {
        int run = 0;
        for (int i = 0; i < nblk; ++i) {
            int v = partial[i];
            partial[i] = run;
            run += v;
        }
        rowptr[N] = E;
    }
}

__global__ void scan_final(const int* __restrict__ deg, const int* __restrict__ partial,
                           int* __restrict__ rowptr, int* __restrict__ cursor,
                           float* __restrict__ dinv, int N) {
    int base = blockIdx.x * 1024;
    int t = threadIdx.x;
    int i0 = base + t * 4;
    int v[4];
    int s = 0;
#pragma unroll
    for (int j = 0; j < 4; ++j) {
        int g = i0 + j;
        v[j] = (g < N) ? deg[g] : 0;
        s += v[j];
    }
    __shared__ int sh[256];
    sh[t] = s;
    __syncthreads();
    for (int off = 1; off < 256; off <<= 1) {
        int val = (t >= off) ? sh[t - off] : 0;
        __syncthreads();
        sh[t] += val;
        __syncthreads();
    }
    int pre = sh[t] - s + partial[blockIdx.x];
#pragma unroll
    for (int j = 0; j < 4; ++j) {
        int g = i0 + j;
        if (g < N) {
            rowptr[g] = pre;
            cursor[g] = pre;
            dinv[g] = rsqrtf((float)v[j] + 1.0f);
            pre += v[j];
        }
    }
}

__global__ void fill_csr(const void* __restrict__ ei, const int* __restrict__ flag,
                         int* __restrict__ cursor, int* __restrict__ col, int E) {
    int e = blockIdx.x * 256 + threadIdx.x;
    if (e >= E) return;
    int s, d;
    load_edge(ei, e, E, *flag, s, d);
    int pos = atomicAdd(&cursor[d], 1);
    col[pos] = s;
}

// ---------------- gather mean (one wave per node, quarter-wave/neighbor) ---
// 4 neighbors in flight; lane = q*16 + sl; each lane reads 16B (8 bf16).
__global__ void gather_mean(const int* __restrict__ rowptr, const int* __restrict__ col,
                            const unsigned short* __restrict__ xbf,
                            unsigned short* __restrict__ meanbf, int N) {
    int node = blockIdx.x * 4 + (threadIdx.x >> 6);
    if (node >= N) return;
    int lane = threadIdx.x & 63;
    int q = lane >> 4;    // neighbor slot 0..3
    int sl = lane & 15;   // column group (8 cols)
    int beg = rowptr[node], end = rowptr[node + 1];
    float a0 = 0.f, a1 = 0.f, a2 = 0.f, a3 = 0.f, a4 = 0.f, a5 = 0.f, a6 = 0.f, a7 = 0.f;
    for (int e = beg; e < end; e += 4) {
        int idx = e + q;
        if (idx < end) {
            int s = col[idx];
            ushort8v v = *(const ushort8v*)(xbf + (size_t)s * DIN + sl * 8);
            a0 += bf2f(v[0]); a1 += bf2f(v[1]); a2 += bf2f(v[2]); a3 += bf2f(v[3]);
            a4 += bf2f(v[4]); a5 += bf2f(v[5]); a6 += bf2f(v[6]); a7 += bf2f(v[7]);
        }
    }
    a0 += __shfl_xor(a0, 16, 64); a0 += __shfl_xor(a0, 32, 64);
    a1 += __shfl_xor(a1, 16, 64); a1 += __shfl_xor(a1, 32, 64);
    a2 += __shfl_xor(a2, 16, 64); a2 += __shfl_xor(a2, 32, 64);
    a3 += __shfl_xor(a3, 16, 64); a3 += __shfl_xor(a3, 32, 64);
    a4 += __shfl_xor(a4, 16, 64); a4 += __shfl_xor(a4, 32, 64);
    a5 += __shfl_xor(a5, 16, 64); a5 += __shfl_xor(a5, 32, 64);
    a6 += __shfl_xor(a6, 16, 64); a6 += __shfl_xor(a6, 32, 64);
    a7 += __shfl_xor(a7, 16, 64); a7 += __shfl_xor(a7, 32, 64);
    if (q == 0) {
        float invd = (end > beg) ? 1.0f / (float)(end - beg) : 0.f;
        ushort8v H;
        H[0] = f2bf_rne(a0 * invd); H[1] = f2bf_rne(a1 * invd);
        H[2] = f2bf_rne(a2 * invd); H[3] = f2bf_rne(a3 * invd);
        H[4] = f2bf_rne(a4 * invd); H[5] = f2bf_rne(a5 * invd);
        H[6] = f2bf_rne(a6 * invd); H[7] = f2bf_rne(a7 * invd);
        *(ushort8v*)(meanbf + (size_t)node * DIN + sl * 8) = H;
    }
}

// ---------------- GEMM (operand-swapped): h^T = Wcat*u^T; hw^T = Wg*h^T ----
// 64 nodes/block (2 tiles), 256 threads (4 waves). Weights prefetched to
// registers as A-fragments; u/h read from LDS as B-fragments.
// D layout: col=node (lane&15), row=feature ((lane>>4)*4+q) -> packed writes.
__global__ __launch_bounds__(256) void sage_gemm(
    const unsigned short* __restrict__ meanbf,
    const unsigned short* __restrict__ xbf,
    const unsigned short* __restrict__ WcH, const unsigned short* __restrict__ WcL,
    const unsigned short* __restrict__ WgH, const unsigned short* __restrict__ WgL,
    const float* __restrict__ bl, unsigned short* __restrict__ hwbf, int N)
{
    __shared__ unsigned short usH[2][32 * U_STR];
    __shared__ unsigned short hsH[32 * H_STR];
    const int tid = threadIdx.x;
    const int wave = tid >> 6;
    const int lane = tid & 63;
    const int lrow = lane & 15;        // A-row(feature) / B-col(node) / D-col(node)
    const int lk8  = (lane >> 4) << 3; // k base within K=32 step
    const int qr   = (lane >> 4) << 2; // D-row (feature) base
    const int n0 = blockIdx.x * 64;

    // ---- prefetch ALL weight fragments (A-side) to registers
    const int f0 = wave * 32 + lrow;   // GEMM1 feature rows, tile 0
    const int f1 = f0 + 16;            // tile 1
    short8v B1[8][4];   // [ks][f0 hi, f0 lo, f1 hi, f1 lo]
#pragma unroll
    for (int ks = 0; ks < 8; ++ks) {
        int kb = ks * 32 + lk8;
        B1[ks][0] = *(const short8v*)(WcH + f0 * 256 + kb);
        B1[ks][1] = *(const short8v*)(WcL + f0 * 256 + kb);
        B1[ks][2] = *(const short8v*)(WcH + f1 * 256 + kb);
        B1[ks][3] = *(const short8v*)(WcL + f1 * 256 + kb);
    }
    const int fg = wave * 16 + lrow;   // GEMM2 feature row
    short8v B2[4][2];   // [ks][hi, lo]
#pragma unroll
    for (int ks = 0; ks < 4; ++ks) {
        int kb = ks * 32 + lk8;
        B2[ks][0] = *(const short8v*)(WgH + fg * 128 + kb);
        B2[ks][1] = *(const short8v*)(WgL + fg * 128 + kb);
    }
    // bias for features wave*32+qr..+3 and wave*32+16+qr..+3
    const float4 bbA = *(const float4*)(bl + wave * 32 + qr);
    const float4 bbB = *(const float4*)(bl + wave * 32 + 16 + qr);

    // ---- cooperative A staging into buf
    auto stage = [&](int buf, int nb) {
        for (int idx = tid; idx < 32 * 32; idx += 256) {
            int n = idx >> 5;
            int c8 = (idx & 31) << 3;
            int node = nb + n;
            if (node >= N) node = N - 1;
            short8v v = (c8 < 128)
                            ? *(const short8v*)(meanbf + (size_t)node * DIN + c8)
                            : *(const short8v*)(xbf + (size_t)node * DIN + (c8 - 128));
            *(short8v*)(&usH[buf][n * U_STR + c8]) = v;
        }
    };

    stage(0, n0);
    __syncthreads();

#pragma unroll
    for (int t = 0; t < 2; ++t) {
        if (t == 0) stage(1, n0 + 32);   // overlap with tile-0 MFMAs

        const int nb = n0 + t * 32;
        float4v acc00 = {0.f, 0.f, 0.f, 0.f};  // feats f0-tile, nodes 0-15
        float4v acc01 = {0.f, 0.f, 0.f, 0.f};  // feats f1-tile, nodes 0-15
        float4v acc10 = {0.f, 0.f, 0.f, 0.f};  // feats f0-tile, nodes 16-31
        float4v acc11 = {0.f, 0.f, 0.f, 0.f};  // feats f1-tile, nodes 16-31

        // ---- GEMM1: acc = Wcat-frag x u-frag  (A=weights, B=activations)
#pragma unroll
        for (int ks = 0; ks < 8; ++ks) {
            int kb = ks * 32 + lk8;
            short8v a0 = *(const short8v*)&usH[t][lrow * U_STR + kb];         // nodes 0-15
            short8v a1 = *(const short8v*)&usH[t][(16 + lrow) * U_STR + kb];  // nodes 16-31
            acc00 = __builtin_amdgcn_mfma_f32_16x16x32_bf16(B1[ks][0], a0, acc00, 0, 0, 0);
            acc00 = __builtin_amdgcn_mfma_f32_16x16x32_bf16(B1[ks][1], a0, acc00, 0, 0, 0);
            acc01 = __builtin_amdgcn_mfma_f32_16x16x32_bf16(B1[ks][2], a0, acc01, 0, 0, 0);
            acc01 = __builtin_amdgcn_mfma_f32_16x16x32_bf16(B1[ks][3], a0, acc01, 0, 0, 0);
            acc10 = __builtin_amdgcn_mfma_f32_16x16x32_bf16(B1[ks][0], a1, acc10, 0, 0, 0);
            acc10 = __builtin_amdgcn_mfma_f32_16x16x32_bf16(B1[ks][1], a1, acc10, 0, 0, 0);
            acc11 = __builtin_amdgcn_mfma_f32_16x16x32_bf16(B1[ks][2], a1, acc11, 0, 0, 0);
            acc11 = __builtin_amdgcn_mfma_f32_16x16x32_bf16(B1[ks][3], a1, acc11, 0, 0, 0);
        }

        __syncthreads();   // previous hsH readers done

        // ---- bias + ReLU -> RNE bf16 h into LDS, PACKED (8B per acc)
        {
            ushort4v p;
            p[0] = f2bf_rne(fmaxf(acc00[0] + bbA.x, 0.f));
            p[1] = f2bf_rne(fmaxf(acc00[1] + bbA.y, 0.f));
            p[2] = f2bf_rne(fmaxf(acc00[2] + bbA.z, 0.f));
            p[3] = f2bf_rne(fmaxf(acc00[3] + bbA.w, 0.f));
            *(ushort4v*)&hsH[lrow * H_STR + wave * 32 + qr] = p;
            p[0] = f2bf_rne(fmaxf(acc01[0] + bbB.x, 0.f));
            p[1] = f2bf_rne(fmaxf(acc01[1] + bbB.y, 0.f));
            p[2] = f2bf_rne(fmaxf(acc01[2] + bbB.z, 0.f));
            p[3] = f2bf_rne(fmaxf(acc01[3] + bbB.w, 0.f));
            *(ushort4v*)&hsH[lrow * H_STR + wave * 32 + 16 + qr] = p;
            p[0] = f2bf_rne(fmaxf(acc10[0] + bbA.x, 0.f));
            p[1] = f2bf_rne(fmaxf(acc10[1] + bbA.y, 0.f));
            p[2] = f2bf_rne(fmaxf(acc10[2] + bbA.z, 0.f));
            p[3] = f2bf_rne(fmaxf(acc10[3] + bbA.w, 0.f));
            *(ushort4v*)&hsH[(16 + lrow) * H_STR + wave * 32 + qr] = p;
            p[0] = f2bf_rne(fmaxf(acc11[0] + bbB.x, 0.f));
            p[1] = f2bf_rne(fmaxf(acc11[1] + bbB.y, 0.f));
            p[2] = f2bf_rne(fmaxf(acc11[2] + bbB.z, 0.f));
            p[3] = f2bf_rne(fmaxf(acc11[3] + bbB.w, 0.f));
            *(ushort4v*)&hsH[(16 + lrow) * H_STR + wave * 32 + 16 + qr] = p;
        }
        __syncthreads();

        // ---- GEMM2: acc2 = Wg-frag x h-frag
        float4v acc2_0 = {0.f, 0.f, 0.f, 0.f};  // feats fg-tile, nodes 0-15
        float4v acc2_1 = {0.f, 0.f, 0.f, 0.f};  // feats fg-tile, nodes 16-31
#pragma unroll
        for (int ks = 0; ks < 4; ++ks) {
            int kb = ks * 32 + lk8;
            short8v a0 = *(const short8v*)&hsH[lrow * H_STR + kb];
            short8v a1 = *(const short8v*)&hsH[(16 + lrow) * H_STR + kb];
            acc2_0 = __builtin_amdgcn_mfma_f32_16x16x32_bf16(B2[ks][0], a0, acc2_0, 0, 0, 0);
            acc2_0 = __builtin_amdgcn_mfma_f32_16x16x32_bf16(B2[ks][1], a0, acc2_0, 0, 0, 0);
            acc2_1 = __builtin_amdgcn_mfma_f32_16x16x32_bf16(B2[ks][0], a1, acc2_1, 0, 0, 0);
            acc2_1 = __builtin_amdgcn_mfma_f32_16x16x32_bf16(B2[ks][1], a1, acc2_1, 0, 0, 0);
        }

        // ---- write hw bf16 PACKED: lane -> node (col), 4 consecutive feats
        {
            int node0 = nb + lrow;
            int node1 = nb + 16 + lrow;
            ushort4v p;
            p[0] = f2bf_rne(acc2_0[0]);
            p[1] = f2bf_rne(acc2_0[1]);
            p[2] = f2bf_rne(acc2_0[2]);
            p[3] = f2bf_rne(acc2_0[3]);
            if (node0 < N) *(ushort4v*)(hwbf + (size_t)node0 * DOUT + wave * 16 + qr) = p;
            p[0] = f2bf_rne(acc2_1[0]);
            p[1] = f2bf_rne(acc2_1[1]);
            p[2] = f2bf_rne(acc2_1[2]);
            p[3] = f2bf_rne(acc2_1[3]);
            if (node1 < N) *(ushort4v*)(hwbf + (size_t)node1 * DOUT + wave * 16 + qr) = p;
        }
    }
}

// ---------------- gather GCN + softmax (one wave/node, quarter-wave/nbr) ---
__global__ void gather_gcn_softmax(const int* __restrict__ rowptr, const int* __restrict__ col,
                                   const unsigned short* __restrict__ hwbf,
                                   const float* __restrict__ dinv,
                                   const float* __restrict__ bg,
                                   float* __restrict__ out, float* __restrict__ soft, int N) {
    int node = blockIdx.x * 4 + (threadIdx.x >> 6);
    if (node >= N) return;
    int lane = threadIdx.x & 63;
    int q = lane >> 4;    // neighbor slot 0..3
    int sl = lane & 15;   // column group (4 cols)
    int beg = rowptr[node], end = rowptr[node + 1];
    float a0 = 0.f, a1 = 0.f, a2 = 0.f, a3 = 0.f;
    for (int e = beg; e < end; e += 4) {
        int idx = e + q;
        if (idx < end) {
            int s = col[idx];
            float w = dinv[s];
            ushort4v v = *(const ushort4v*)(hwbf + (size_t)s * DOUT + sl * 4);
            a0 += w * bf2f(v[0]);
            a1 += w * bf2f(v[1]);
            a2 += w * bf2f(v[2]);
            a3 += w * bf2f(v[3]);
        }
    }
    a0 += __shfl_xor(a0, 16, 64); a0 += __shfl_xor(a0, 32, 64);
    a1 += __shfl_xor(a1, 16, 64); a1 += __shfl_xor(a1, 32, 64);
    a2 += __shfl_xor(a2, 16, 64); a2 += __shfl_xor(a2, 32, 64);
    a3 += __shfl_xor(a3, 16, 64); a3 += __shfl_xor(a3, 32, 64);

    float di = dinv[node];
    float d2 = di * di;
    ushort4v sv = *(const ushort4v*)(hwbf + (size_t)node * DOUT + sl * 4);
    float4 bb = *(const float4*)(bg + sl * 4);
    float v0 = di * a0 + d2 * bf2f(sv[0]) + bb.x;
    float v1 = di * a1 + d2 * bf2f(sv[1]) + bb.y;
    float v2 = di * a2 + d2 * bf2f(sv[2]) + bb.z;
    float v3 = di * a3 + d2 * bf2f(sv[3]) + bb.w;

    float m = fmaxf(fmaxf(v0, v1), fmaxf(v2, v3));
#pragma unroll
    for (int mask = 8; mask; mask >>= 1) m = fmaxf(m, __shfl_xor(m, mask, 64));
    float e0 = __expf(v0 - m), e1 = __expf(v1 - m), e2 = __expf(v2 - m), e3 = __expf(v3 - m);
    float s = e0 + e1 + e2 + e3;
#pragma unroll
    for (int mask = 8; mask; mask >>= 1) s += __shfl_xor(s, mask, 64);
    if (q == 0) {
        float inv = 1.0f / s;
        float4 ov = make_float4(v0, v1, v2, v3);
        float4 pv = make_float4(e0 * inv, e1 * inv, e2 * inv, e3 * inv);
        *(float4*)(out + (size_t)node * DOUT + sl * 4) = ov;
        *(float4*)(soft + (size_t)node * DOUT + sl * 4) = pv;
    }
}

// ---------------------------------------------------------------------------
extern "C" void kernel_launch(void* const* d_in, const int* in_sizes, int n_in,
                              void* d_out, int out_size, void* d_ws, size_t ws_size,
                              hipStream_t stream) {
    const float* x  = (const float*)d_in[0];
    const void*  ei = d_in[1];
    const float* Wl = (const float*)d_in[2];
    const float* bl = (const float*)d_in[3];
    const float* Wr = (const float*)d_in[4];
    const float* Wg = (const float*)d_in[5];
    const float* bg = (const float*)d_in[6];
    const int N = in_sizes[0] / DIN;
    const int E = in_sizes[1] / 2;
    float* out = (float*)d_out;

    char* ws = (char*)d_ws;
    size_t off = 0;
    auto alloc = [&](size_t bytes) {
        void* p = ws + off;
        off += (bytes + 255) / 256 * 256;
        return p;
    };
    int*   flag    = (int*)alloc(4);
    int*   deg     = (int*)alloc((size_t)N * 4);
    float* dinv    = (float*)alloc((size_t)N * 4);
    int*   rowptr  = (int*)alloc((size_t)(N + 1) * 4);
    int*   cursor  = (int*)alloc((size_t)N * 4);
    int*   colv    = (int*)alloc((size_t)E * 4);
    int*   partial = (int*)alloc(1024 * 4);
    unsigned short* WcH = (unsigned short*)alloc(128 * 256 * 2);
    unsigned short* WcL = (unsigned short*)alloc(128 * 256 * 2);
    unsigned short* WgH = (unsigned short*)alloc(64 * 128 * 2);
    unsigned short* WgL = (unsigned short*)alloc(64 * 128 * 2);
    unsigned short* xbf    = (unsigned short*)alloc((size_t)N * DIN * 2);
    unsigned short* meanbf = (unsigned short*)alloc((size_t)N * DIN * 2);
    unsigned short* hwbf   = (unsigned short*)alloc((size_t)N * DOUT * 2);
    (void)ws_size; (void)n_in; (void)out_size;

    float* soft = out + (size_t)N * DOUT;

    const int nblk = (N + 1023) / 1024;

    hipMemsetAsync(deg, 0, (size_t)N * 4, stream);

    detect_idx_kernel<<<1, 256, 0, stream>>>(ei, 2 * E, flag);
    {
        size_t xElems = (size_t)N * DIN;
        size_t total = 128 * 256 + 64 * 128 + (xElems + 3) / 4;
        prep_all<<<(int)((total + 255) / 256), 256, 0, stream>>>(
            Wl, Wr, Wg, WcH, WcL, WgH, WgL, x, xbf, xElems);
    }
    count_deg<<<(E + 255) / 256, 256, 0, stream>>>(ei, flag, deg, E);
    scan_partial<<<nblk, 256, 0, stream>>>(deg, partial, N);
    scan_offsets<<<1, 64, 0, stream>>>(partial, nblk, rowptr, N, E);
    scan_final<<<nblk, 256, 0, stream>>>(deg, partial, rowptr, cursor, dinv, N);
    fill_csr<<<(E + 255) / 256, 256, 0, stream>>>(ei, flag, cursor, colv, E);
    gather_mean<<<(N + 3) / 4, 256, 0, stream>>>(rowptr, colv, xbf, meanbf, N);
    sage_gemm<<<(N + 63) / 64, 256, 0, stream>>>(meanbf, xbf, WcH, WcL, WgH, WgL, bl, hwbf, N);
    gather_gcn_softmax<<<(N + 3) / 4, 256, 0, stream>>>(rowptr, colv, hwbf, dinv, bg, out, soft, N);
}

// Round 9
// 213.173 us; speedup vs baseline: 1.1193x; 1.1193x over previous
//
#include <hip/hip_runtime.h>
#include <math.h>

// GraphSAGE (mean) + GCN + softmax. Activations RNE-bf16, weights split
// hi/lo bf16, f32 accumulate. MFMA operand-swapped (A=weights, B=activations).
// sage_gemm: 8-wave blocks, 16 features/wave -> weights truly register-resident,
// grid-strided tiles, double-buffered LDS.
// N=100000, E=625000, D_IN=D_H=128, D_OUT=64 (derived from in_sizes).

#define DIN 128
#define DH  128
#define DOUT 64
#define NT  32      // nodes per tile
#define U_STR 264   // 256 + 8 pad (ushort)
#define H_STR 136   // 128 + 8 pad (ushort)

typedef __attribute__((ext_vector_type(8))) short short8v;            // 8 bf16
typedef __attribute__((ext_vector_type(4))) float float4v;            // MFMA acc
typedef __attribute__((ext_vector_type(8))) unsigned short ushort8v;  // 8 bf16
typedef __attribute__((ext_vector_type(4))) unsigned short ushort4v;  // 4 bf16

__device__ __forceinline__ void splitf(float a, unsigned short& hi, unsigned short& lo) {
    unsigned ai = __float_as_uint(a);
    hi = (unsigned short)(ai >> 16);
    float r = a - __uint_as_float(ai & 0xffff0000u);
    lo = (unsigned short)(__float_as_uint(r) >> 16);
}

__device__ __forceinline__ unsigned short f2bf_rne(float f) {
    unsigned u = __float_as_uint(f);
    return (unsigned short)((u + 0x7fffu + ((u >> 16) & 1u)) >> 16);
}

__device__ __forceinline__ float bf2f(unsigned short u) {
    return __uint_as_float(((unsigned)u) << 16);
}

// ---------------- edge-index dtype detection (int64 vs int32) --------------
__global__ void detect_idx_kernel(const void* ei, int twoE, int* flag) {
    __shared__ int ok;
    if (threadIdx.x == 0) ok = 1;
    __syncthreads();
    const int* p = (const int*)ei;
    for (int i = threadIdx.x; i < 512; i += blockDim.x) {
        long long pos = 1 + ((long long)i * (long long)(twoE - 2)) / 512;
        pos |= 1;
        if (pos < twoE && p[pos] != 0) ok = 0;
    }
    __syncthreads();
    if (threadIdx.x == 0) *flag = ok;  // 1 => int64, 0 => int32
}

__device__ __forceinline__ void load_edge(const void* ei, int e, int E, int is64,
                                          int& s, int& d) {
    if (is64) {
        const long long* p = (const long long*)ei;
        s = (int)p[e];
        d = (int)p[E + e];
    } else {
        const int* p = (const int*)ei;
        s = p[e];
        d = p[E + e];
    }
}

// ---------------- prep: weight split + x -> bf16 ---------------------------
__global__ void prep_all(const float* __restrict__ Wl, const float* __restrict__ Wr,
                         const float* __restrict__ Wg,
                         unsigned short* __restrict__ WcH, unsigned short* __restrict__ WcL,
                         unsigned short* __restrict__ WgH, unsigned short* __restrict__ WgL,
                         const float* __restrict__ x, unsigned short* __restrict__ xbf,
                         size_t xElems) {
    size_t idx = (size_t)blockIdx.x * 256 + threadIdx.x;
    if (idx < 128 * 256) {
        int o = (int)(idx >> 8), k = (int)(idx & 255);
        float v = (k < 128) ? Wl[o * 128 + k] : Wr[o * 128 + (k - 128)];
        unsigned short h, l;
        splitf(v, h, l);
        WcH[idx] = h; WcL[idx] = l;
    } else if (idx < 128 * 256 + 64 * 128) {
        size_t j = idx - 128 * 256;
        unsigned short h, l;
        splitf(Wg[j], h, l);
        WgH[j] = h; WgL[j] = l;
    } else {
        size_t j = (idx - (128 * 256 + 64 * 128)) * 4;
        if (j < xElems) {
            float4 v = *(const float4*)(x + j);
            ushort4v o;
            o[0] = f2bf_rne(v.x);
            o[1] = f2bf_rne(v.y);
            o[2] = f2bf_rne(v.z);
            o[3] = f2bf_rne(v.w);
            *(ushort4v*)(xbf + j) = o;
        }
    }
}

// ---------------- CSR build -----------------------------------------------
__global__ void count_deg(const void* __restrict__ ei, const int* __restrict__ flag,
                          int* __restrict__ deg, int E) {
    int e = blockIdx.x * 256 + threadIdx.x;
    if (e >= E) return;
    int s, d;
    load_edge(ei, e, E, *flag, s, d);
    atomicAdd(&deg[d], 1);
}

__global__ void scan_partial(const int* __restrict__ deg, int* __restrict__ partial, int N) {
    int base = blockIdx.x * 1024;
    int t = threadIdx.x;
    int s = 0;
    for (int i = t; i < 1024; i += 256) {
        int g = base + i;
        if (g < N) s += deg[g];
    }
    __shared__ int sh[256];
    sh[t] = s;
    __syncthreads();
    for (int off = 128; off; off >>= 1) {
        if (t < off) sh[t] += sh[t + off];
        __syncthreads();
    }
    if (t == 0) partial[blockIdx.x] = sh[0];
}

__global__ void scan_offsets(int* partial, int nblk, int* rowptr, int N, int E) {
    if (threadIdx.x == 0 && blockIdx.x == 0) {
        int run = 0;
        for (int i = 0; i < nblk; ++i) {
            int v = partial[i];
            partial[i] = run;
            run += v;
        }
        rowptr[N] = E;
    }
}

__global__ void scan_final(const int* __restrict__ deg, const int* __restrict__ partial,
                           int* __restrict__ rowptr, int* __restrict__ cursor,
                           float* __restrict__ dinv, int N) {
    int base = blockIdx.x * 1024;
    int t = threadIdx.x;
    int i0 = base + t * 4;
    int v[4];
    int s = 0;
#pragma unroll
    for (int j = 0; j < 4; ++j) {
        int g = i0 + j;
        v[j] = (g < N) ? deg[g] : 0;
        s += v[j];
    }
    __shared__ int sh[256];
    sh[t] = s;
    __syncthreads();
    for (int off = 1; off < 256; off <<= 1) {
        int val = (t >= off) ? sh[t - off] : 0;
        __syncthreads();
        sh[t] += val;
        __syncthreads();
    }
    int pre = sh[t] - s + partial[blockIdx.x];
#pragma unroll
    for (int j = 0; j < 4; ++j) {
        int g = i0 + j;
        if (g < N) {
            rowptr[g] = pre;
            cursor[g] = pre;
            dinv[g] = rsqrtf((float)v[j] + 1.0f);
            pre += v[j];
        }
    }
}

__global__ void fill_csr(const void* __restrict__ ei, const int* __restrict__ flag,
                         int* __restrict__ cursor, int* __restrict__ col, int E) {
    int e = blockIdx.x * 256 + threadIdx.x;
    if (e >= E) return;
    int s, d;
    load_edge(ei, e, E, *flag, s, d);
    int pos = atomicAdd(&cursor[d], 1);
    col[pos] = s;
}

// ---------------- gather mean (one wave per node, quarter-wave/neighbor) ---
__global__ void gather_mean(const int* __restrict__ rowptr, const int* __restrict__ col,
                            const unsigned short* __restrict__ xbf,
                            unsigned short* __restrict__ meanbf, int N) {
    int node = blockIdx.x * 4 + (threadIdx.x >> 6);
    if (node >= N) return;
    int lane = threadIdx.x & 63;
    int q = lane >> 4;    // neighbor slot 0..3
    int sl = lane & 15;   // column group (8 cols)
    int beg = rowptr[node], end = rowptr[node + 1];
    float a0 = 0.f, a1 = 0.f, a2 = 0.f, a3 = 0.f, a4 = 0.f, a5 = 0.f, a6 = 0.f, a7 = 0.f;
    for (int e = beg; e < end; e += 4) {
        int idx = e + q;
        if (idx < end) {
            int s = col[idx];
            ushort8v v = *(const ushort8v*)(xbf + (size_t)s * DIN + sl * 8);
            a0 += bf2f(v[0]); a1 += bf2f(v[1]); a2 += bf2f(v[2]); a3 += bf2f(v[3]);
            a4 += bf2f(v[4]); a5 += bf2f(v[5]); a6 += bf2f(v[6]); a7 += bf2f(v[7]);
        }
    }
    a0 += __shfl_xor(a0, 16, 64); a0 += __shfl_xor(a0, 32, 64);
    a1 += __shfl_xor(a1, 16, 64); a1 += __shfl_xor(a1, 32, 64);
    a2 += __shfl_xor(a2, 16, 64); a2 += __shfl_xor(a2, 32, 64);
    a3 += __shfl_xor(a3, 16, 64); a3 += __shfl_xor(a3, 32, 64);
    a4 += __shfl_xor(a4, 16, 64); a4 += __shfl_xor(a4, 32, 64);
    a5 += __shfl_xor(a5, 16, 64); a5 += __shfl_xor(a5, 32, 64);
    a6 += __shfl_xor(a6, 16, 64); a6 += __shfl_xor(a6, 32, 64);
    a7 += __shfl_xor(a7, 16, 64); a7 += __shfl_xor(a7, 32, 64);
    if (q == 0) {
        float invd = (end > beg) ? 1.0f / (float)(end - beg) : 0.f;
        ushort8v H;
        H[0] = f2bf_rne(a0 * invd); H[1] = f2bf_rne(a1 * invd);
        H[2] = f2bf_rne(a2 * invd); H[3] = f2bf_rne(a3 * invd);
        H[4] = f2bf_rne(a4 * invd); H[5] = f2bf_rne(a5 * invd);
        H[6] = f2bf_rne(a6 * invd); H[7] = f2bf_rne(a7 * invd);
        *(ushort8v*)(meanbf + (size_t)node * DIN + sl * 8) = H;
    }
}

// ---------------- GEMM (swapped): h^T = Wcat*u^T; hw^T = Wg*h^T ------------
// 512 threads = 8 waves. GEMM1: wave w -> features [w*16, w*16+16), all 32
// nodes of the tile (B1 = 64 VGPRs, register-resident). GEMM2: wave w ->
// feature-tile (w&3), node-tile (w>>2) (B2 = 32 VGPRs). Grid-strided tiles,
// double-buffered usH/hsH, 2 barriers per tile.
__global__ __launch_bounds__(512, 4) void sage_gemm(
    const unsigned short* __restrict__ meanbf,
    const unsigned short* __restrict__ xbf,
    const unsigned short* __restrict__ WcH, const unsigned short* __restrict__ WcL,
    const unsigned short* __restrict__ WgH, const unsigned short* __restrict__ WgL,
    const float* __restrict__ bl, unsigned short* __restrict__ hwbf,
    int N, int ntiles)
{
    __shared__ unsigned short usH[2][32 * U_STR];
    __shared__ unsigned short hsH[2][32 * H_STR];
    const int tid = threadIdx.x;
    const int wave = tid >> 6;        // 0..7
    const int lane = tid & 63;
    const int lrow = lane & 15;       // A-row(feature) / B-col(node) / D-col(node)
    const int lk8  = (lane >> 4) << 3;
    const int qr   = (lane >> 4) << 2;

    // ---- GEMM1 weights: 16 features per wave, hi+lo (64 VGPRs)
    const int f1 = wave * 16 + lrow;
    short8v B1[8][2];
#pragma unroll
    for (int ks = 0; ks < 8; ++ks) {
        int kb = ks * 32 + lk8;
        B1[ks][0] = *(const short8v*)(WcH + f1 * 256 + kb);
        B1[ks][1] = *(const short8v*)(WcL + f1 * 256 + kb);
    }
    // ---- GEMM2 weights: feature-tile (wave&3), hi+lo (32 VGPRs)
    const int fw = (wave & 3) * 16;
    const int nw = (wave >> 2) * 16;
    const int f2 = fw + lrow;
    short8v B2[4][2];
#pragma unroll
    for (int ks = 0; ks < 4; ++ks) {
        int kb = ks * 32 + lk8;
        B2[ks][0] = *(const short8v*)(WgH + f2 * 128 + kb);
        B2[ks][1] = *(const short8v*)(WgL + f2 * 128 + kb);
    }
    const float4 bb = *(const float4*)(bl + wave * 16 + qr);

    auto stage = [&](int buf, int tile) {
        int nb = tile * NT;
        for (int idx = tid; idx < 32 * 32; idx += 512) {
            int n = idx >> 5;
            int c8 = (idx & 31) << 3;
            int node = nb + n;
            if (node >= N) node = N - 1;
            short8v v = (c8 < 128)
                            ? *(const short8v*)(meanbf + (size_t)node * DIN + c8)
                            : *(const short8v*)(xbf + (size_t)node * DIN + (c8 - 128));
            *(short8v*)(&usH[buf][n * U_STR + c8]) = v;
        }
    };

    int tile = blockIdx.x;
    if (tile >= ntiles) return;
    int buf = 0;
    stage(0, tile);
    __syncthreads();

    for (; tile < ntiles; tile += gridDim.x) {
        int nxt = tile + gridDim.x;
        if (nxt < ntiles) stage(buf ^ 1, nxt);   // overlap with this tile's MFMAs

        // ---- GEMM1: acc0 = W x u (nodes 0-15), acc1 = (nodes 16-31)
        float4v acc0 = {0.f, 0.f, 0.f, 0.f};
        float4v acc1 = {0.f, 0.f, 0.f, 0.f};
#pragma unroll
        for (int ks = 0; ks < 8; ++ks) {
            int kb = ks * 32 + lk8;
            short8v a0 = *(const short8v*)&usH[buf][lrow * U_STR + kb];
            short8v a1 = *(const short8v*)&usH[buf][(16 + lrow) * U_STR + kb];
            acc0 = __builtin_amdgcn_mfma_f32_16x16x32_bf16(B1[ks][0], a0, acc0, 0, 0, 0);
            acc0 = __builtin_amdgcn_mfma_f32_16x16x32_bf16(B1[ks][1], a0, acc0, 0, 0, 0);
            acc1 = __builtin_amdgcn_mfma_f32_16x16x32_bf16(B1[ks][0], a1, acc1, 0, 0, 0);
            acc1 = __builtin_amdgcn_mfma_f32_16x16x32_bf16(B1[ks][1], a1, acc1, 0, 0, 0);
        }
        __syncthreads();

        // ---- bias + ReLU -> bf16 h (packed 8B writes): h[node][feat]
        {
            ushort4v p;
            p[0] = f2bf_rne(fmaxf(acc0[0] + bb.x, 0.f));
            p[1] = f2bf_rne(fmaxf(acc0[1] + bb.y, 0.f));
            p[2] = f2bf_rne(fmaxf(acc0[2] + bb.z, 0.f));
            p[3] = f2bf_rne(fmaxf(acc0[3] + bb.w, 0.f));
            *(ushort4v*)&hsH[buf][lrow * H_STR + wave * 16 + qr] = p;
            p[0] = f2bf_rne(fmaxf(acc1[0] + bb.x, 0.f));
            p[1] = f2bf_rne(fmaxf(acc1[1] + bb.y, 0.f));
            p[2] = f2bf_rne(fmaxf(acc1[2] + bb.z, 0.f));
            p[3] = f2bf_rne(fmaxf(acc1[3] + bb.w, 0.f));
            *(ushort4v*)&hsH[buf][(16 + lrow) * H_STR + wave * 16 + qr] = p;
        }
        __syncthreads();

        // ---- GEMM2: acc2 = Wg x h  (feature-tile fw, node-tile nw)
        float4v acc2 = {0.f, 0.f, 0.f, 0.f};
#pragma unroll
        for (int ks = 0; ks < 4; ++ks) {
            int kb = ks * 32 + lk8;
            short8v a = *(const short8v*)&hsH[buf][(nw + lrow) * H_STR + kb];
            acc2 = __builtin_amdgcn_mfma_f32_16x16x32_bf16(B2[ks][0], a, acc2, 0, 0, 0);
            acc2 = __builtin_amdgcn_mfma_f32_16x16x32_bf16(B2[ks][1], a, acc2, 0, 0, 0);
        }

        // ---- write hw bf16 packed: node = tile*NT + nw + lrow, feats fw+qr..+3
        {
            int node = tile * NT + nw + lrow;
            if (node < N) {
                ushort4v p;
                p[0] = f2bf_rne(acc2[0]);
                p[1] = f2bf_rne(acc2[1]);
                p[2] = f2bf_rne(acc2[2]);
                p[3] = f2bf_rne(acc2[3]);
                *(ushort4v*)(hwbf + (size_t)node * DOUT + fw + qr) = p;
            }
        }
        buf ^= 1;
    }
}

// ---------------- gather GCN + softmax (one wave/node, quarter-wave/nbr) ---
__global__ void gather_gcn_softmax(const int* __restrict__ rowptr, const int* __restrict__ col,
                                   const unsigned short* __restrict__ hwbf,
                                   const float* __restrict__ dinv,
                                   const float* __restrict__ bg,
                                   float* __restrict__ out, float* __restrict__ soft, int N) {
    int node = blockIdx.x * 4 + (threadIdx.x >> 6);
    if (node >= N) return;
    int lane = threadIdx.x & 63;
    int q = lane >> 4;    // neighbor slot 0..3
    int sl = lane & 15;   // column group (4 cols)
    int beg = rowptr[node], end = rowptr[node + 1];
    float a0 = 0.f, a1 = 0.f, a2 = 0.f, a3 = 0.f;
    for (int e = beg; e < end; e += 4) {
        int idx = e + q;
        if (idx < end) {
            int s = col[idx];
            float w = dinv[s];
            ushort4v v = *(const ushort4v*)(hwbf + (size_t)s * DOUT + sl * 4);
            a0 += w * bf2f(v[0]);
            a1 += w * bf2f(v[1]);
            a2 += w * bf2f(v[2]);
            a3 += w * bf2f(v[3]);
        }
    }
    a0 += __shfl_xor(a0, 16, 64); a0 += __shfl_xor(a0, 32, 64);
    a1 += __shfl_xor(a1, 16, 64); a1 += __shfl_xor(a1, 32, 64);
    a2 += __shfl_xor(a2, 16, 64); a2 += __shfl_xor(a2, 32, 64);
    a3 += __shfl_xor(a3, 16, 64); a3 += __shfl_xor(a3, 32, 64);

    float di = dinv[node];
    float d2 = di * di;
    ushort4v sv = *(const ushort4v*)(hwbf + (size_t)node * DOUT + sl * 4);
    float4 bb = *(const float4*)(bg + sl * 4);
    float v0 = di * a0 + d2 * bf2f(sv[0]) + bb.x;
    float v1 = di * a1 + d2 * bf2f(sv[1]) + bb.y;
    float v2 = di * a2 + d2 * bf2f(sv[2]) + bb.z;
    float v3 = di * a3 + d2 * bf2f(sv[3]) + bb.w;

    float m = fmaxf(fmaxf(v0, v1), fmaxf(v2, v3));
#pragma unroll
    for (int mask = 8; mask; mask >>= 1) m = fmaxf(m, __shfl_xor(m, mask, 64));
    float e0 = __expf(v0 - m), e1 = __expf(v1 - m), e2 = __expf(v2 - m), e3 = __expf(v3 - m);
    float s = e0 + e1 + e2 + e3;
#pragma unroll
    for (int mask = 8; mask; mask >>= 1) s += __shfl_xor(s, mask, 64);
    if (q == 0) {
        float inv = 1.0f / s;
        float4 ov = make_float4(v0, v1, v2, v3);
        float4 pv = make_float4(e0 * inv, e1 * inv, e2 * inv, e3 * inv);
        *(float4*)(out + (size_t)node * DOUT + sl * 4) = ov;
        *(float4*)(soft + (size_t)node * DOUT + sl * 4) = pv;
    }
}

// ---------------------------------------------------------------------------
extern "C" void kernel_launch(void* const* d_in, const int* in_sizes, int n_in,
                              void* d_out, int out_size, void* d_ws, size_t ws_size,
                              hipStream_t stream) {
    const float* x  = (const float*)d_in[0];
    const void*  ei = d_in[1];
    const float* Wl = (const float*)d_in[2];
    const float* bl = (const float*)d_in[3];
    const float* Wr = (const float*)d_in[4];
    const float* Wg = (const float*)d_in[5];
    const float* bg = (const float*)d_in[6];
    const int N = in_sizes[0] / DIN;
    const int E = in_sizes[1] / 2;
    float* out = (float*)d_out;

    char* ws = (char*)d_ws;
    size_t off = 0;
    auto alloc = [&](size_t bytes) {
        void* p = ws + off;
        off += (bytes + 255) / 256 * 256;
        return p;
    };
    int*   flag    = (int*)alloc(4);
    int*   deg     = (int*)alloc((size_t)N * 4);
    float* dinv    = (float*)alloc((size_t)N * 4);
    int*   rowptr  = (int*)alloc((size_t)(N + 1) * 4);
    int*   cursor  = (int*)alloc((size_t)N * 4);
    int*   colv    = (int*)alloc((size_t)E * 4);
    int*   partial = (int*)alloc(1024 * 4);
    unsigned short* WcH = (unsigned short*)alloc(128 * 256 * 2);
    unsigned short* WcL = (unsigned short*)alloc(128 * 256 * 2);
    unsigned short* WgH = (unsigned short*)alloc(64 * 128 * 2);
    unsigned short* WgL = (unsigned short*)alloc(64 * 128 * 2);
    unsigned short* xbf    = (unsigned short*)alloc((size_t)N * DIN * 2);
    unsigned short* meanbf = (unsigned short*)alloc((size_t)N * DIN * 2);
    unsigned short* hwbf   = (unsigned short*)alloc((size_t)N * DOUT * 2);
    (void)ws_size; (void)n_in; (void)out_size;

    float* soft = out + (size_t)N * DOUT;

    const int nblk = (N + 1023) / 1024;
    const int ntiles = (N + NT - 1) / NT;

    hipMemsetAsync(deg, 0, (size_t)N * 4, stream);

    detect_idx_kernel<<<1, 256, 0, stream>>>(ei, 2 * E, flag);
    {
        size_t xElems = (size_t)N * DIN;
        size_t total = 128 * 256 + 64 * 128 + (xElems + 3) / 4;
        prep_all<<<(int)((total + 255) / 256), 256, 0, stream>>>(
            Wl, Wr, Wg, WcH, WcL, WgH, WgL, x, xbf, xElems);
    }
    count_deg<<<(E + 255) / 256, 256, 0, stream>>>(ei, flag, deg, E);
    scan_partial<<<nblk, 256, 0, stream>>>(deg, partial, N);
    scan_offsets<<<1, 64, 0, stream>>>(partial, nblk, rowptr, N, E);
    scan_final<<<nblk, 256, 0, stream>>>(deg, partial, rowptr, cursor, dinv, N);
    fill_csr<<<(E + 255) / 256, 256, 0, stream>>>(ei, flag, cursor, colv, E);
    gather_mean<<<(N + 3) / 4, 256, 0, stream>>>(rowptr, colv, xbf, meanbf, N);
    sage_gemm<<<512, 512, 0, stream>>>(meanbf, xbf, WcH, WcL, WgH, WgL, bl, hwbf, N, ntiles);
    gather_gcn_softmax<<<(N + 3) / 4, 256, 0, stream>>>(rowptr, colv, hwbf, dinv, bg, out, soft, N);
}

// Round 10
// 189.647 us; speedup vs baseline: 1.2581x; 1.1241x over previous
//
#include <hip/hip_runtime.h>
#include <math.h>

// GraphSAGE (mean) + GCN + softmax. Activations RNE-bf16, weights split
// hi/lo bf16, f32 accumulate. MFMA operand-swapped (A=weights, B=activations).
// hw stored pre-scaled by dinv -> GCN gather is a pure sum.
// N=100000, E=625000, D_IN=D_H=128, D_OUT=64 (derived from in_sizes).

#define DIN 128
#define DH  128
#define DOUT 64
#define NT  32      // nodes per GEMM tile
#define U_STR 264   // 256 + 8 pad (ushort)
#define H_STR 136   // 128 + 8 pad (ushort)

typedef __attribute__((ext_vector_type(8))) short short8v;            // 8 bf16
typedef __attribute__((ext_vector_type(4))) float float4v;            // MFMA acc
typedef __attribute__((ext_vector_type(8))) unsigned short ushort8v;  // 8 bf16
typedef __attribute__((ext_vector_type(4))) unsigned short ushort4v;  // 4 bf16

__device__ __forceinline__ void splitf(float a, unsigned short& hi, unsigned short& lo) {
    unsigned ai = __float_as_uint(a);
    hi = (unsigned short)(ai >> 16);
    float r = a - __uint_as_float(ai & 0xffff0000u);
    lo = (unsigned short)(__float_as_uint(r) >> 16);
}

__device__ __forceinline__ unsigned short f2bf_rne(float f) {
    unsigned u = __float_as_uint(f);
    return (unsigned short)((u + 0x7fffu + ((u >> 16) & 1u)) >> 16);
}

__device__ __forceinline__ float bf2f(unsigned short u) {
    return __uint_as_float(((unsigned)u) << 16);
}

// ---------------- edge-index dtype detection (int64 vs int32) --------------
__global__ void detect_idx_kernel(const void* ei, int twoE, int* flag) {
    __shared__ int ok;
    if (threadIdx.x == 0) ok = 1;
    __syncthreads();
    const int* p = (const int*)ei;
    for (int i = threadIdx.x; i < 512; i += blockDim.x) {
        long long pos = 1 + ((long long)i * (long long)(twoE - 2)) / 512;
        pos |= 1;
        if (pos < twoE && p[pos] != 0) ok = 0;
    }
    __syncthreads();
    if (threadIdx.x == 0) *flag = ok;  // 1 => int64, 0 => int32
}

__device__ __forceinline__ void load_edge(const void* ei, int e, int E, int is64,
                                          int& s, int& d) {
    if (is64) {
        const long long* p = (const long long*)ei;
        s = (int)p[e];
        d = (int)p[E + e];
    } else {
        const int* p = (const int*)ei;
        s = p[e];
        d = p[E + e];
    }
}

// ---------------- prep: weight split + x -> bf16 ---------------------------
__global__ void prep_all(const float* __restrict__ Wl, const float* __restrict__ Wr,
                         const float* __restrict__ Wg,
                         unsigned short* __restrict__ WcH, unsigned short* __restrict__ WcL,
                         unsigned short* __restrict__ WgH, unsigned short* __restrict__ WgL,
                         const float* __restrict__ x, unsigned short* __restrict__ xbf,
                         size_t xElems) {
    size_t idx = (size_t)blockIdx.x * 256 + threadIdx.x;
    if (idx < 128 * 256) {
        int o = (int)(idx >> 8), k = (int)(idx & 255);
        float v = (k < 128) ? Wl[o * 128 + k] : Wr[o * 128 + (k - 128)];
        unsigned short h, l;
        splitf(v, h, l);
        WcH[idx] = h; WcL[idx] = l;
    } else if (idx < 128 * 256 + 64 * 128) {
        size_t j = idx - 128 * 256;
        unsigned short h, l;
        splitf(Wg[j], h, l);
        WgH[j] = h; WgL[j] = l;
    } else {
        size_t j = (idx - (128 * 256 + 64 * 128)) * 4;
        if (j < xElems) {
            float4 v = *(const float4*)(x + j);
            ushort4v o;
            o[0] = f2bf_rne(v.x);
            o[1] = f2bf_rne(v.y);
            o[2] = f2bf_rne(v.z);
            o[3] = f2bf_rne(v.w);
            *(ushort4v*)(xbf + j) = o;
        }
    }
}

// ---------------- CSR build -----------------------------------------------
__global__ void count_deg(const void* __restrict__ ei, const int* __restrict__ flag,
                          int* __restrict__ deg, int E) {
    int e = blockIdx.x * 256 + threadIdx.x;
    if (e >= E) return;
    int s, d;
    load_edge(ei, e, E, *flag, s, d);
    atomicAdd(&deg[d], 1);
}

__global__ void scan_partial(const int* __restrict__ deg, int* __restrict__ partial, int N) {
    int base = blockIdx.x * 1024;
    int t = threadIdx.x;
    int s = 0;
    for (int i = t; i < 1024; i += 256) {
        int g = base + i;
        if (g < N) s += deg[g];
    }
    __shared__ int sh[256];
    sh[t] = s;
    __syncthreads();
    for (int off = 128; off; off >>= 1) {
        if (t < off) sh[t] += sh[t + off];
        __syncthreads();
    }
    if (t == 0) partial[blockIdx.x] = sh[0];
}

// local scan + block prefix (computed in-kernel) + cursor + dinv; rowptr[N]=E
__global__ void scan_final(const int* __restrict__ deg, const int* __restrict__ partial,
                           int* __restrict__ rowptr, int* __restrict__ cursor,
                           float* __restrict__ dinv, int N, int E) {
    __shared__ int sh[256];
    int base = blockIdx.x * 1024;
    int t = threadIdx.x;

    // phase 1: block prefix = sum of partial[0..blockIdx.x)
    int ps = 0;
    for (int i = t; i < blockIdx.x; i += 256) ps += partial[i];
    sh[t] = ps;
    __syncthreads();
    for (int off = 128; off; off >>= 1) {
        if (t < off) sh[t] += sh[t + off];
        __syncthreads();
    }
    int blockpre = sh[0];
    __syncthreads();

    // phase 2: local exclusive scan over this block's 1024 elements
    int i0 = base + t * 4;
    int v[4];
    int s = 0;
#pragma unroll
    for (int j = 0; j < 4; ++j) {
        int g = i0 + j;
        v[j] = (g < N) ? deg[g] : 0;
        s += v[j];
    }
    sh[t] = s;
    __syncthreads();
    for (int off = 1; off < 256; off <<= 1) {
        int val = (t >= off) ? sh[t - off] : 0;
        __syncthreads();
        sh[t] += val;
        __syncthreads();
    }
    int pre = sh[t] - s + blockpre;
#pragma unroll
    for (int j = 0; j < 4; ++j) {
        int g = i0 + j;
        if (g < N) {
            rowptr[g] = pre;
            cursor[g] = pre;
            dinv[g] = rsqrtf((float)v[j] + 1.0f);
            pre += v[j];
        }
    }
    if (blockIdx.x == 0 && t == 0) rowptr[N] = E;
}

__global__ void fill_csr(const void* __restrict__ ei, const int* __restrict__ flag,
                         int* __restrict__ cursor, int* __restrict__ col, int E) {
    int e = blockIdx.x * 256 + threadIdx.x;
    if (e >= E) return;
    int s, d;
    load_edge(ei, e, E, *flag, s, d);
    int pos = atomicAdd(&cursor[d], 1);
    col[pos] = s;
}

// ---------------- gather mean: quarter-wave (16 lanes) per node ------------
// lane sl owns 8 features; serial over edges; 4 independent nodes per wave.
__global__ void gather_mean(const int* __restrict__ rowptr, const int* __restrict__ col,
                            const unsigned short* __restrict__ xbf,
                            unsigned short* __restrict__ meanbf, int N) {
    int node = blockIdx.x * 16 + (threadIdx.x >> 4);
    if (node >= N) return;
    int sl = threadIdx.x & 15;
    int beg = rowptr[node], end = rowptr[node + 1];
    float a0 = 0.f, a1 = 0.f, a2 = 0.f, a3 = 0.f, a4 = 0.f, a5 = 0.f, a6 = 0.f, a7 = 0.f;
    for (int e = beg; e < end; ++e) {
        int s = col[e];
        ushort8v v = *(const ushort8v*)(xbf + (size_t)s * DIN + sl * 8);
        a0 += bf2f(v[0]); a1 += bf2f(v[1]); a2 += bf2f(v[2]); a3 += bf2f(v[3]);
        a4 += bf2f(v[4]); a5 += bf2f(v[5]); a6 += bf2f(v[6]); a7 += bf2f(v[7]);
    }
    float invd = (end > beg) ? 1.0f / (float)(end - beg) : 0.f;
    ushort8v H;
    H[0] = f2bf_rne(a0 * invd); H[1] = f2bf_rne(a1 * invd);
    H[2] = f2bf_rne(a2 * invd); H[3] = f2bf_rne(a3 * invd);
    H[4] = f2bf_rne(a4 * invd); H[5] = f2bf_rne(a5 * invd);
    H[6] = f2bf_rne(a6 * invd); H[7] = f2bf_rne(a7 * invd);
    *(ushort8v*)(meanbf + (size_t)node * DIN + sl * 8) = H;
}

// ---------------- GEMM (swapped): h^T = Wcat*u^T; hw^T = dinv*(Wg*h^T) -----
// 512 threads = 8 waves. GEMM1: wave w -> features [w*16,+16) (B1 reg-resident).
// GEMM2: wave w -> feature-tile (w&3), node-tile (w>>2). Grid-strided tiles,
// double-buffered LDS. hw written PRE-SCALED by dinv[node].
__global__ __launch_bounds__(512, 4) void sage_gemm(
    const unsigned short* __restrict__ meanbf,
    const unsigned short* __restrict__ xbf,
    const unsigned short* __restrict__ WcH, const unsigned short* __restrict__ WcL,
    const unsigned short* __restrict__ WgH, const unsigned short* __restrict__ WgL,
    const float* __restrict__ bl, const float* __restrict__ dinv,
    unsigned short* __restrict__ hwbf, int N, int ntiles)
{
    __shared__ unsigned short usH[2][32 * U_STR];
    __shared__ unsigned short hsH[2][32 * H_STR];
    const int tid = threadIdx.x;
    const int wave = tid >> 6;        // 0..7
    const int lane = tid & 63;
    const int lrow = lane & 15;       // A-row(feature) / B-col(node) / D-col(node)
    const int lk8  = (lane >> 4) << 3;
    const int qr   = (lane >> 4) << 2;

    // ---- GEMM1 weights: 16 features per wave, hi+lo (64 VGPRs)
    const int f1 = wave * 16 + lrow;
    short8v B1[8][2];
#pragma unroll
    for (int ks = 0; ks < 8; ++ks) {
        int kb = ks * 32 + lk8;
        B1[ks][0] = *(const short8v*)(WcH + f1 * 256 + kb);
        B1[ks][1] = *(const short8v*)(WcL + f1 * 256 + kb);
    }
    // ---- GEMM2 weights: feature-tile (wave&3), hi+lo (32 VGPRs)
    const int fw = (wave & 3) * 16;
    const int nw = (wave >> 2) * 16;
    const int f2 = fw + lrow;
    short8v B2[4][2];
#pragma unroll
    for (int ks = 0; ks < 4; ++ks) {
        int kb = ks * 32 + lk8;
        B2[ks][0] = *(const short8v*)(WgH + f2 * 128 + kb);
        B2[ks][1] = *(const short8v*)(WgL + f2 * 128 + kb);
    }
    const float4 bb = *(const float4*)(bl + wave * 16 + qr);

    auto stage = [&](int buf, int tile) {
        int nb = tile * NT;
        for (int idx = tid; idx < 32 * 32; idx += 512) {
            int n = idx >> 5;
            int c8 = (idx & 31) << 3;
            int node = nb + n;
            if (node >= N) node = N - 1;
            short8v v = (c8 < 128)
                            ? *(const short8v*)(meanbf + (size_t)node * DIN + c8)
                            : *(const short8v*)(xbf + (size_t)node * DIN + (c8 - 128));
            *(short8v*)(&usH[buf][n * U_STR + c8]) = v;
        }
    };

    int tile = blockIdx.x;
    if (tile >= ntiles) return;
    int buf = 0;
    stage(0, tile);
    __syncthreads();

    for (; tile < ntiles; tile += gridDim.x) {
        int nxt = tile + gridDim.x;
        if (nxt < ntiles) stage(buf ^ 1, nxt);   // overlap with this tile's MFMAs

        // ---- GEMM1: acc0 = W x u (nodes 0-15), acc1 = (nodes 16-31)
        float4v acc0 = {0.f, 0.f, 0.f, 0.f};
        float4v acc1 = {0.f, 0.f, 0.f, 0.f};
#pragma unroll
        for (int ks = 0; ks < 8; ++ks) {
            int kb = ks * 32 + lk8;
            short8v a0 = *(const short8v*)&usH[buf][lrow * U_STR + kb];
            short8v a1 = *(const short8v*)&usH[buf][(16 + lrow) * U_STR + kb];
            acc0 = __builtin_amdgcn_mfma_f32_16x16x32_bf16(B1[ks][0], a0, acc0, 0, 0, 0);
            acc0 = __builtin_amdgcn_mfma_f32_16x16x32_bf16(B1[ks][1], a0, acc0, 0, 0, 0);
            acc1 = __builtin_amdgcn_mfma_f32_16x16x32_bf16(B1[ks][0], a1, acc1, 0, 0, 0);
            acc1 = __builtin_amdgcn_mfma_f32_16x16x32_bf16(B1[ks][1], a1, acc1, 0, 0, 0);
        }
        __syncthreads();

        // ---- bias + ReLU -> bf16 h (packed 8B writes): h[node][feat]
        {
            ushort4v p;
            p[0] = f2bf_rne(fmaxf(acc0[0] + bb.x, 0.f));
            p[1] = f2bf_rne(fmaxf(acc0[1] + bb.y, 0.f));
            p[2] = f2bf_rne(fmaxf(acc0[2] + bb.z, 0.f));
            p[3] = f2bf_rne(fmaxf(acc0[3] + bb.w, 0.f));
            *(ushort4v*)&hsH[buf][lrow * H_STR + wave * 16 + qr] = p;
            p[0] = f2bf_rne(fmaxf(acc1[0] + bb.x, 0.f));
            p[1] = f2bf_rne(fmaxf(acc1[1] + bb.y, 0.f));
            p[2] = f2bf_rne(fmaxf(acc1[2] + bb.z, 0.f));
            p[3] = f2bf_rne(fmaxf(acc1[3] + bb.w, 0.f));
            *(ushort4v*)&hsH[buf][(16 + lrow) * H_STR + wave * 16 + qr] = p;
        }
        __syncthreads();

        // ---- GEMM2: acc2 = Wg x h  (feature-tile fw, node-tile nw)
        float4v acc2 = {0.f, 0.f, 0.f, 0.f};
#pragma unroll
        for (int ks = 0; ks < 4; ++ks) {
            int kb = ks * 32 + lk8;
            short8v a = *(const short8v*)&hsH[buf][(nw + lrow) * H_STR + kb];
            acc2 = __builtin_amdgcn_mfma_f32_16x16x32_bf16(B2[ks][0], a, acc2, 0, 0, 0);
            acc2 = __builtin_amdgcn_mfma_f32_16x16x32_bf16(B2[ks][1], a, acc2, 0, 0, 0);
        }

        // ---- write hw bf16 packed, PRE-SCALED by dinv[node]
        {
            int node = tile * NT + nw + lrow;
            if (node < N) {
                float dv = dinv[node];
                ushort4v p;
                p[0] = f2bf_rne(dv * acc2[0]);
                p[1] = f2bf_rne(dv * acc2[1]);
                p[2] = f2bf_rne(dv * acc2[2]);
                p[3] = f2bf_rne(dv * acc2[3]);
                *(ushort4v*)(hwbf + (size_t)node * DOUT + fw + qr) = p;
            }
        }
        buf ^= 1;
    }
}

// ---------------- gather GCN + softmax: quarter-wave per node --------------
// out = dinv[d] * (sum_nbrs hw_scaled[s] + hw_scaled[d]) + bg; then softmax.
__global__ void gather_gcn_softmax(const int* __restrict__ rowptr, const int* __restrict__ col,
                                   const unsigned short* __restrict__ hwbf,
                                   const float* __restrict__ dinv,
                                   const float* __restrict__ bg,
                                   float* __restrict__ out, float* __restrict__ soft, int N) {
    int node = blockIdx.x * 16 + (threadIdx.x >> 4);
    if (node >= N) return;
    int sl = threadIdx.x & 15;
    int beg = rowptr[node], end = rowptr[node + 1];

    // self term (pre-scaled) starts the accumulator
    ushort4v sv = *(const ushort4v*)(hwbf + (size_t)node * DOUT + sl * 4);
    float a0 = bf2f(sv[0]), a1 = bf2f(sv[1]), a2 = bf2f(sv[2]), a3 = bf2f(sv[3]);

    for (int e = beg; e < end; ++e) {
        int s = col[e];
        ushort4v v = *(const ushort4v*)(hwbf + (size_t)s * DOUT + sl * 4);
        a0 += bf2f(v[0]);
        a1 += bf2f(v[1]);
        a2 += bf2f(v[2]);
        a3 += bf2f(v[3]);
    }

    float di = dinv[node];
    float4 bb = *(const float4*)(bg + sl * 4);
    float v0 = di * a0 + bb.x;
    float v1 = di * a1 + bb.y;
    float v2 = di * a2 + bb.z;
    float v3 = di * a3 + bb.w;

    // softmax over 64 cols held by 16 lanes x 4
    float m = fmaxf(fmaxf(v0, v1), fmaxf(v2, v3));
#pragma unroll
    for (int mask = 8; mask; mask >>= 1) m = fmaxf(m, __shfl_xor(m, mask, 64));
    float e0 = __expf(v0 - m), e1 = __expf(v1 - m), e2 = __expf(v2 - m), e3 = __expf(v3 - m);
    float s = e0 + e1 + e2 + e3;
#pragma unroll
    for (int mask = 8; mask; mask >>= 1) s += __shfl_xor(s, mask, 64);
    float inv = 1.0f / s;
    *(float4*)(out + (size_t)node * DOUT + sl * 4) = make_float4(v0, v1, v2, v3);
    *(float4*)(soft + (size_t)node * DOUT + sl * 4) =
        make_float4(e0 * inv, e1 * inv, e2 * inv, e3 * inv);
}

// ---------------------------------------------------------------------------
extern "C" void kernel_launch(void* const* d_in, const int* in_sizes, int n_in,
                              void* d_out, int out_size, void* d_ws, size_t ws_size,
                              hipStream_t stream) {
    const float* x  = (const float*)d_in[0];
    const void*  ei = d_in[1];
    const float* Wl = (const float*)d_in[2];
    const float* bl = (const float*)d_in[3];
    const float* Wr = (const float*)d_in[4];
    const float* Wg = (const float*)d_in[5];
    const float* bg = (const float*)d_in[6];
    const int N = in_sizes[0] / DIN;
    const int E = in_sizes[1] / 2;
    float* out = (float*)d_out;

    char* ws = (char*)d_ws;
    size_t off = 0;
    auto alloc = [&](size_t bytes) {
        void* p = ws + off;
        off += (bytes + 255) / 256 * 256;
        return p;
    };
    int*   flag    = (int*)alloc(4);
    int*   deg     = (int*)alloc((size_t)N * 4);
    float* dinv    = (float*)alloc((size_t)N * 4);
    int*   rowptr  = (int*)alloc((size_t)(N + 1) * 4);
    int*   cursor  = (int*)alloc((size_t)N * 4);
    int*   colv    = (int*)alloc((size_t)E * 4);
    int*   partial = (int*)alloc(1024 * 4);
    unsigned short* WcH = (unsigned short*)alloc(128 * 256 * 2);
    unsigned short* WcL = (unsigned short*)alloc(128 * 256 * 2);
    unsigned short* WgH = (unsigned short*)alloc(64 * 128 * 2);
    unsigned short* WgL = (unsigned short*)alloc(64 * 128 * 2);
    unsigned short* xbf    = (unsigned short*)alloc((size_t)N * DIN * 2);
    unsigned short* meanbf = (unsigned short*)alloc((size_t)N * DIN * 2);
    unsigned short* hwbf   = (unsigned short*)alloc((size_t)N * DOUT * 2);
    (void)ws_size; (void)n_in; (void)out_size;

    float* soft = out + (size_t)N * DOUT;

    const int nblk = (N + 1023) / 1024;
    const int ntiles = (N + NT - 1) / NT;

    hipMemsetAsync(deg, 0, (size_t)N * 4, stream);

    detect_idx_kernel<<<1, 256, 0, stream>>>(ei, 2 * E, flag);
    {
        size_t xElems = (size_t)N * DIN;
        size_t total = 128 * 256 + 64 * 128 + (xElems + 3) / 4;
        prep_all<<<(int)((total + 255) / 256), 256, 0, stream>>>(
            Wl, Wr, Wg, WcH, WcL, WgH, WgL, x, xbf, xElems);
    }
    count_deg<<<(E + 255) / 256, 256, 0, stream>>>(ei, flag, deg, E);
    scan_partial<<<nblk, 256, 0, stream>>>(deg, partial, N);
    scan_final<<<nblk, 256, 0, stream>>>(deg, partial, rowptr, cursor, dinv, N, E);
    fill_csr<<<(E + 255) / 256, 256, 0, stream>>>(ei, flag, cursor, colv, E);
    gather_mean<<<(N + 15) / 16, 256, 0, stream>>>(rowptr, colv, xbf, meanbf, N);
    sage_gemm<<<512, 512, 0, stream>>>(meanbf, xbf, WcH, WcL, WgH, WgL, bl, dinv, hwbf, N, ntiles);
    gather_gcn_softmax<<<(N + 15) / 16, 256, 0, stream>>>(rowptr, colv, hwbf, dinv, bg, out, soft, N);
}

// Round 11
// 188.919 us; speedup vs baseline: 1.2630x; 1.0039x over previous
//
#include <hip/hip_runtime.h>
#include <math.h>

// GraphSAGE (mean) + GCN + softmax. Activations RNE-bf16, weights split
// hi/lo bf16, f32 accumulate. MFMA operand-swapped (A=weights, B=activations).
// hw stored pre-scaled by dinv -> GCN gather is a pure sum.
// deg zeroing fused into init kernel (hipMemsetAsync fill was 39 us!).
// N=100000, E=625000, D_IN=D_H=128, D_OUT=64 (derived from in_sizes).

#define DIN 128
#define DH  128
#define DOUT 64
#define NT  32      // nodes per GEMM tile
#define U_STR 264   // 256 + 8 pad (ushort)
#define H_STR 136   // 128 + 8 pad (ushort)

typedef __attribute__((ext_vector_type(8))) short short8v;            // 8 bf16
typedef __attribute__((ext_vector_type(4))) float float4v;            // MFMA acc
typedef __attribute__((ext_vector_type(8))) unsigned short ushort8v;  // 8 bf16
typedef __attribute__((ext_vector_type(4))) unsigned short ushort4v;  // 4 bf16

__device__ __forceinline__ void splitf(float a, unsigned short& hi, unsigned short& lo) {
    unsigned ai = __float_as_uint(a);
    hi = (unsigned short)(ai >> 16);
    float r = a - __uint_as_float(ai & 0xffff0000u);
    lo = (unsigned short)(__float_as_uint(r) >> 16);
}

__device__ __forceinline__ unsigned short f2bf_rne(float f) {
    unsigned u = __float_as_uint(f);
    return (unsigned short)((u + 0x7fffu + ((u >> 16) & 1u)) >> 16);
}

__device__ __forceinline__ float bf2f(unsigned short u) {
    return __uint_as_float(((unsigned)u) << 16);
}

// ---------------- init: zero deg (grid-stride) + edge dtype detect ---------
__global__ void init_deg_detect(const void* ei, int twoE, int* flag,
                                int* __restrict__ deg, int N) {
    int i = blockIdx.x * 256 + threadIdx.x;
    int base = i * 4;
    if (base + 3 < N) {
        *(int4*)(deg + base) = make_int4(0, 0, 0, 0);
    } else {
        for (int j = base; j < N && j < base + 4; ++j) deg[j] = 0;
    }
    if (blockIdx.x == 0) {
        __shared__ int ok;
        if (threadIdx.x == 0) ok = 1;
        __syncthreads();
        const int* p = (const int*)ei;
        for (int k = threadIdx.x; k < 512; k += 256) {
            long long pos = 1 + ((long long)k * (long long)(twoE - 2)) / 512;
            pos |= 1;  // odd int32 word of an int64 lane
            if (pos < twoE && p[pos] != 0) ok = 0;
        }
        __syncthreads();
        if (threadIdx.x == 0) *flag = ok;  // 1 => int64, 0 => int32
    }
}

__device__ __forceinline__ void load_edge(const void* ei, int e, int E, int is64,
                                          int& s, int& d) {
    if (is64) {
        const long long* p = (const long long*)ei;
        s = (int)p[e];
        d = (int)p[E + e];
    } else {
        const int* p = (const int*)ei;
        s = p[e];
        d = p[E + e];
    }
}

// ---------------- prep: weight split + x -> bf16 ---------------------------
__global__ void prep_all(const float* __restrict__ Wl, const float* __restrict__ Wr,
                         const float* __restrict__ Wg,
                         unsigned short* __restrict__ WcH, unsigned short* __restrict__ WcL,
                         unsigned short* __restrict__ WgH, unsigned short* __restrict__ WgL,
                         const float* __restrict__ x, unsigned short* __restrict__ xbf,
                         size_t xElems) {
    size_t idx = (size_t)blockIdx.x * 256 + threadIdx.x;
    if (idx < 128 * 256) {
        int o = (int)(idx >> 8), k = (int)(idx & 255);
        float v = (k < 128) ? Wl[o * 128 + k] : Wr[o * 128 + (k - 128)];
        unsigned short h, l;
        splitf(v, h, l);
        WcH[idx] = h; WcL[idx] = l;
    } else if (idx < 128 * 256 + 64 * 128) {
        size_t j = idx - 128 * 256;
        unsigned short h, l;
        splitf(Wg[j], h, l);
        WgH[j] = h; WgL[j] = l;
    } else {
        size_t j = (idx - (128 * 256 + 64 * 128)) * 4;
        if (j < xElems) {
            float4 v = *(const float4*)(x + j);
            ushort4v o;
            o[0] = f2bf_rne(v.x);
            o[1] = f2bf_rne(v.y);
            o[2] = f2bf_rne(v.z);
            o[3] = f2bf_rne(v.w);
            *(ushort4v*)(xbf + j) = o;
        }
    }
}

// ---------------- CSR build -----------------------------------------------
__global__ void count_deg(const void* __restrict__ ei, const int* __restrict__ flag,
                          int* __restrict__ deg, int E) {
    int e = blockIdx.x * 256 + threadIdx.x;
    if (e >= E) return;
    int s, d;
    load_edge(ei, e, E, *flag, s, d);
    atomicAdd(&deg[d], 1);
}

__global__ void scan_partial(const int* __restrict__ deg, int* __restrict__ partial, int N) {
    int base = blockIdx.x * 1024;
    int t = threadIdx.x;
    int s = 0;
    for (int i = t; i < 1024; i += 256) {
        int g = base + i;
        if (g < N) s += deg[g];
    }
    __shared__ int sh[256];
    sh[t] = s;
    __syncthreads();
    for (int off = 128; off; off >>= 1) {
        if (t < off) sh[t] += sh[t + off];
        __syncthreads();
    }
    if (t == 0) partial[blockIdx.x] = sh[0];
}

// local scan + block prefix (computed in-kernel) + cursor + dinv; rowptr[N]=E
__global__ void scan_final(const int* __restrict__ deg, const int* __restrict__ partial,
                           int* __restrict__ rowptr, int* __restrict__ cursor,
                           float* __restrict__ dinv, int N, int E) {
    __shared__ int sh[256];
    int base = blockIdx.x * 1024;
    int t = threadIdx.x;

    // phase 1: block prefix = sum of partial[0..blockIdx.x)
    int ps = 0;
    for (int i = t; i < blockIdx.x; i += 256) ps += partial[i];
    sh[t] = ps;
    __syncthreads();
    for (int off = 128; off; off >>= 1) {
        if (t < off) sh[t] += sh[t + off];
        __syncthreads();
    }
    int blockpre = sh[0];
    __syncthreads();

    // phase 2: local exclusive scan over this block's 1024 elements
    int i0 = base + t * 4;
    int v[4];
    int s = 0;
#pragma unroll
    for (int j = 0; j < 4; ++j) {
        int g = i0 + j;
        v[j] = (g < N) ? deg[g] : 0;
        s += v[j];
    }
    sh[t] = s;
    __syncthreads();
    for (int off = 1; off < 256; off <<= 1) {
        int val = (t >= off) ? sh[t - off] : 0;
        __syncthreads();
        sh[t] += val;
        __syncthreads();
    }
    int pre = sh[t] - s + blockpre;
#pragma unroll
    for (int j = 0; j < 4; ++j) {
        int g = i0 + j;
        if (g < N) {
            rowptr[g] = pre;
            cursor[g] = pre;
            dinv[g] = rsqrtf((float)v[j] + 1.0f);
            pre += v[j];
        }
    }
    if (blockIdx.x == 0 && t == 0) rowptr[N] = E;
}

__global__ void fill_csr(const void* __restrict__ ei, const int* __restrict__ flag,
                         int* __restrict__ cursor, int* __restrict__ col, int E) {
    int e = blockIdx.x * 256 + threadIdx.x;
    if (e >= E) return;
    int s, d;
    load_edge(ei, e, E, *flag, s, d);
    int pos = atomicAdd(&cursor[d], 1);
    col[pos] = s;
}

// ---------------- gather mean: quarter-wave (16 lanes) per node ------------
__global__ void gather_mean(const int* __restrict__ rowptr, const int* __restrict__ col,
                            const unsigned short* __restrict__ xbf,
                            unsigned short* __restrict__ meanbf, int N) {
    int node = blockIdx.x * 16 + (threadIdx.x >> 4);
    if (node >= N) return;
    int sl = threadIdx.x & 15;
    int beg = rowptr[node], end = rowptr[node + 1];
    float a0 = 0.f, a1 = 0.f, a2 = 0.f, a3 = 0.f, a4 = 0.f, a5 = 0.f, a6 = 0.f, a7 = 0.f;
    for (int e = beg; e < end; ++e) {
        int s = col[e];
        ushort8v v = *(const ushort8v*)(xbf + (size_t)s * DIN + sl * 8);
        a0 += bf2f(v[0]); a1 += bf2f(v[1]); a2 += bf2f(v[2]); a3 += bf2f(v[3]);
        a4 += bf2f(v[4]); a5 += bf2f(v[5]); a6 += bf2f(v[6]); a7 += bf2f(v[7]);
    }
    float invd = (end > beg) ? 1.0f / (float)(end - beg) : 0.f;
    ushort8v H;
    H[0] = f2bf_rne(a0 * invd); H[1] = f2bf_rne(a1 * invd);
    H[2] = f2bf_rne(a2 * invd); H[3] = f2bf_rne(a3 * invd);
    H[4] = f2bf_rne(a4 * invd); H[5] = f2bf_rne(a5 * invd);
    H[6] = f2bf_rne(a6 * invd); H[7] = f2bf_rne(a7 * invd);
    *(ushort8v*)(meanbf + (size_t)node * DIN + sl * 8) = H;
}

// ---------------- GEMM (swapped): h^T = Wcat*u^T; hw^T = dinv*(Wg*h^T) -----
__global__ __launch_bounds__(512, 4) void sage_gemm(
    const unsigned short* __restrict__ meanbf,
    const unsigned short* __restrict__ xbf,
    const unsigned short* __restrict__ WcH, const unsigned short* __restrict__ WcL,
    const unsigned short* __restrict__ WgH, const unsigned short* __restrict__ WgL,
    const float* __restrict__ bl, const float* __restrict__ dinv,
    unsigned short* __restrict__ hwbf, int N, int ntiles)
{
    __shared__ unsigned short usH[2][32 * U_STR];
    __shared__ unsigned short hsH[2][32 * H_STR];
    const int tid = threadIdx.x;
    const int wave = tid >> 6;        // 0..7
    const int lane = tid & 63;
    const int lrow = lane & 15;       // A-row(feature) / B-col(node) / D-col(node)
    const int lk8  = (lane >> 4) << 3;
    const int qr   = (lane >> 4) << 2;

    // ---- GEMM1 weights: 16 features per wave, hi+lo (64 VGPRs)
    const int f1 = wave * 16 + lrow;
    short8v B1[8][2];
#pragma unroll
    for (int ks = 0; ks < 8; ++ks) {
        int kb = ks * 32 + lk8;
        B1[ks][0] = *(const short8v*)(WcH + f1 * 256 + kb);
        B1[ks][1] = *(const short8v*)(WcL + f1 * 256 + kb);
    }
    // ---- GEMM2 weights: feature-tile (wave&3), hi+lo (32 VGPRs)
    const int fw = (wave & 3) * 16;
    const int nw = (wave >> 2) * 16;
    const int f2 = fw + lrow;
    short8v B2[4][2];
#pragma unroll
    for (int ks = 0; ks < 4; ++ks) {
        int kb = ks * 32 + lk8;
        B2[ks][0] = *(const short8v*)(WgH + f2 * 128 + kb);
        B2[ks][1] = *(const short8v*)(WgL + f2 * 128 + kb);
    }
    const float4 bb = *(const float4*)(bl + wave * 16 + qr);

    auto stage = [&](int buf, int tile) {
        int nb = tile * NT;
        for (int idx = tid; idx < 32 * 32; idx += 512) {
            int n = idx >> 5;
            int c8 = (idx & 31) << 3;
            int node = nb + n;
            if (node >= N) node = N - 1;
            short8v v = (c8 < 128)
                            ? *(const short8v*)(meanbf + (size_t)node * DIN + c8)
                            : *(const short8v*)(xbf + (size_t)node * DIN + (c8 - 128));
            *(short8v*)(&usH[buf][n * U_STR + c8]) = v;
        }
    };

    int tile = blockIdx.x;
    if (tile >= ntiles) return;
    int buf = 0;
    stage(0, tile);
    __syncthreads();

    for (; tile < ntiles; tile += gridDim.x) {
        int nxt = tile + gridDim.x;
        if (nxt < ntiles) stage(buf ^ 1, nxt);   // overlap with this tile's MFMAs

        // ---- GEMM1: acc0 = W x u (nodes 0-15), acc1 = (nodes 16-31)
        float4v acc0 = {0.f, 0.f, 0.f, 0.f};
        float4v acc1 = {0.f, 0.f, 0.f, 0.f};
#pragma unroll
        for (int ks = 0; ks < 8; ++ks) {
            int kb = ks * 32 + lk8;
            short8v a0 = *(const short8v*)&usH[buf][lrow * U_STR + kb];
            short8v a1 = *(const short8v*)&usH[buf][(16 + lrow) * U_STR + kb];
            acc0 = __builtin_amdgcn_mfma_f32_16x16x32_bf16(B1[ks][0], a0, acc0, 0, 0, 0);
            acc0 = __builtin_amdgcn_mfma_f32_16x16x32_bf16(B1[ks][1], a0, acc0, 0, 0, 0);
            acc1 = __builtin_amdgcn_mfma_f32_16x16x32_bf16(B1[ks][0], a1, acc1, 0, 0, 0);
            acc1 = __builtin_amdgcn_mfma_f32_16x16x32_bf16(B1[ks][1], a1, acc1, 0, 0, 0);
        }
        __syncthreads();

        // ---- bias + ReLU -> bf16 h (packed 8B writes): h[node][feat]
        {
            ushort4v p;
            p[0] = f2bf_rne(fmaxf(acc0[0] + bb.x, 0.f));
            p[1] = f2bf_rne(fmaxf(acc0[1] + bb.y, 0.f));
            p[2] = f2bf_rne(fmaxf(acc0[2] + bb.z, 0.f));
            p[3] = f2bf_rne(fmaxf(acc0[3] + bb.w, 0.f));
            *(ushort4v*)&hsH[buf][lrow * H_STR + wave * 16 + qr] = p;
            p[0] = f2bf_rne(fmaxf(acc1[0] + bb.x, 0.f));
            p[1] = f2bf_rne(fmaxf(acc1[1] + bb.y, 0.f));
            p[2] = f2bf_rne(fmaxf(acc1[2] + bb.z, 0.f));
            p[3] = f2bf_rne(fmaxf(acc1[3] + bb.w, 0.f));
            *(ushort4v*)&hsH[buf][(16 + lrow) * H_STR + wave * 16 + qr] = p;
        }
        __syncthreads();

        // ---- GEMM2: acc2 = Wg x h  (feature-tile fw, node-tile nw)
        float4v acc2 = {0.f, 0.f, 0.f, 0.f};
#pragma unroll
        for (int ks = 0; ks < 4; ++ks) {
            int kb = ks * 32 + lk8;
            short8v a = *(const short8v*)&hsH[buf][(nw + lrow) * H_STR + kb];
            acc2 = __builtin_amdgcn_mfma_f32_16x16x32_bf16(B2[ks][0], a, acc2, 0, 0, 0);
            acc2 = __builtin_amdgcn_mfma_f32_16x16x32_bf16(B2[ks][1], a, acc2, 0, 0, 0);
        }

        // ---- write hw bf16 packed, PRE-SCALED by dinv[node]
        {
            int node = tile * NT + nw + lrow;
            if (node < N) {
                float dv = dinv[node];
                ushort4v p;
                p[0] = f2bf_rne(dv * acc2[0]);
                p[1] = f2bf_rne(dv * acc2[1]);
                p[2] = f2bf_rne(dv * acc2[2]);
                p[3] = f2bf_rne(dv * acc2[3]);
                *(ushort4v*)(hwbf + (size_t)node * DOUT + fw + qr) = p;
            }
        }
        buf ^= 1;
    }
}

// ---------------- gather GCN + softmax: quarter-wave per node --------------
__global__ void gather_gcn_softmax(const int* __restrict__ rowptr, const int* __restrict__ col,
                                   const unsigned short* __restrict__ hwbf,
                                   const float* __restrict__ dinv,
                                   const float* __restrict__ bg,
                                   float* __restrict__ out, float* __restrict__ soft, int N) {
    int node = blockIdx.x * 16 + (threadIdx.x >> 4);
    if (node >= N) return;
    int sl = threadIdx.x & 15;
    int beg = rowptr[node], end = rowptr[node + 1];

    // self term (pre-scaled) starts the accumulator
    ushort4v sv = *(const ushort4v*)(hwbf + (size_t)node * DOUT + sl * 4);
    float a0 = bf2f(sv[0]), a1 = bf2f(sv[1]), a2 = bf2f(sv[2]), a3 = bf2f(sv[3]);

    for (int e = beg; e < end; ++e) {
        int s = col[e];
        ushort4v v = *(const ushort4v*)(hwbf + (size_t)s * DOUT + sl * 4);
        a0 += bf2f(v[0]);
        a1 += bf2f(v[1]);
        a2 += bf2f(v[2]);
        a3 += bf2f(v[3]);
    }

    float di = dinv[node];
    float4 bb = *(const float4*)(bg + sl * 4);
    float v0 = di * a0 + bb.x;
    float v1 = di * a1 + bb.y;
    float v2 = di * a2 + bb.z;
    float v3 = di * a3 + bb.w;

    // softmax over 64 cols held by 16 lanes x 4
    float m = fmaxf(fmaxf(v0, v1), fmaxf(v2, v3));
#pragma unroll
    for (int mask = 8; mask; mask >>= 1) m = fmaxf(m, __shfl_xor(m, mask, 64));
    float e0 = __expf(v0 - m), e1 = __expf(v1 - m), e2 = __expf(v2 - m), e3 = __expf(v3 - m);
    float s = e0 + e1 + e2 + e3;
#pragma unroll
    for (int mask = 8; mask; mask >>= 1) s += __shfl_xor(s, mask, 64);
    float inv = 1.0f / s;
    *(float4*)(out + (size_t)node * DOUT + sl * 4) = make_float4(v0, v1, v2, v3);
    *(float4*)(soft + (size_t)node * DOUT + sl * 4) =
        make_float4(e0 * inv, e1 * inv, e2 * inv, e3 * inv);
}

// ---------------------------------------------------------------------------
extern "C" void kernel_launch(void* const* d_in, const int* in_sizes, int n_in,
                              void* d_out, int out_size, void* d_ws, size_t ws_size,
                              hipStream_t stream) {
    const float* x  = (const float*)d_in[0];
    const void*  ei = d_in[1];
    const float* Wl = (const float*)d_in[2];
    const float* bl = (const float*)d_in[3];
    const float* Wr = (const float*)d_in[4];
    const float* Wg = (const float*)d_in[5];
    const float* bg = (const float*)d_in[6];
    const int N = in_sizes[0] / DIN;
    const int E = in_sizes[1] / 2;
    float* out = (float*)d_out;

    char* ws = (char*)d_ws;
    size_t off = 0;
    auto alloc = [&](size_t bytes) {
        void* p = ws + off;
        off += (bytes + 255) / 256 * 256;
        return p;
    };
    int*   flag    = (int*)alloc(4);
    int*   deg     = (int*)alloc((size_t)N * 4);
    float* dinv    = (float*)alloc((size_t)N * 4);
    int*   rowptr  = (int*)alloc((size_t)(N + 1) * 4);
    int*   cursor  = (int*)alloc((size_t)N * 4);
    int*   colv    = (int*)alloc((size_t)E * 4);
    int*   partial = (int*)alloc(1024 * 4);
    unsigned short* WcH = (unsigned short*)alloc(128 * 256 * 2);
    unsigned short* WcL = (unsigned short*)alloc(128 * 256 * 2);
    unsigned short* WgH = (unsigned short*)alloc(64 * 128 * 2);
    unsigned short* WgL = (unsigned short*)alloc(64 * 128 * 2);
    unsigned short* xbf    = (unsigned short*)alloc((size_t)N * DIN * 2);
    unsigned short* meanbf = (unsigned short*)alloc((size_t)N * DIN * 2);
    unsigned short* hwbf   = (unsigned short*)alloc((size_t)N * DOUT * 2);
    (void)ws_size; (void)n_in; (void)out_size;

    float* soft = out + (size_t)N * DOUT;

    const int nblk = (N + 1023) / 1024;
    const int ntiles = (N + NT - 1) / NT;

    init_deg_detect<<<(N / 4 + 255) / 256 + 1, 256, 0, stream>>>(ei, 2 * E, flag, deg, N);
    {
        size_t xElems = (size_t)N * DIN;
        size_t total = 128 * 256 + 64 * 128 + (xElems + 3) / 4;
        prep_all<<<(int)((total + 255) / 256), 256, 0, stream>>>(
            Wl, Wr, Wg, WcH, WcL, WgH, WgL, x, xbf, xElems);
    }
    count_deg<<<(E + 255) / 256, 256, 0, stream>>>(ei, flag, deg, E);
    scan_partial<<<nblk, 256, 0, stream>>>(deg, partial, N);
    scan_final<<<nblk, 256, 0, stream>>>(deg, partial, rowptr, cursor, dinv, N, E);
    fill_csr<<<(E + 255) / 256, 256, 0, stream>>>(ei, flag, cursor, colv, E);
    gather_mean<<<(N + 15) / 16, 256, 0, stream>>>(rowptr, colv, xbf, meanbf, N);
    sage_gemm<<<512, 512, 0, stream>>>(meanbf, xbf, WcH, WcL, WgH, WgL, bl, dinv, hwbf, N, ntiles);
    gather_gcn_softmax<<<(N + 15) / 16, 256, 0, stream>>>(rowptr, colv, hwbf, dinv, bg, out, soft, N);
}

// Round 12
// 151.350 us; speedup vs baseline: 1.5765x; 1.2482x over previous
//
#include <hip/hip_runtime.h>
#include <math.h>

// GraphSAGE (mean) + GCN + softmax. Activations RNE-bf16, weights split
// hi/lo bf16, f32 accumulate. MFMA operand-swapped (A=weights, B=activations).
// hw stored pre-scaled by dinv -> GCN gather is a pure sum.
// CSR replaced by fixed-stride adjacency (24 slots/node) + overflow list,
// built in ONE XCD-partitioned pass; cursor doubles as degree array.
// N=100000, E=625000, D_IN=D_H=128, D_OUT=64 (derived from in_sizes).

#define DIN 128
#define DH  128
#define DOUT 64
#define NT  32      // nodes per GEMM tile
#define FIX 24      // fixed adjacency slots per node
#define U_STR 264   // 256 + 8 pad (ushort)
#define H_STR 136   // 128 + 8 pad (ushort)

typedef __attribute__((ext_vector_type(8))) short short8v;            // 8 bf16
typedef __attribute__((ext_vector_type(4))) float float4v;            // MFMA acc
typedef __attribute__((ext_vector_type(8))) unsigned short ushort8v;  // 8 bf16
typedef __attribute__((ext_vector_type(4))) unsigned short ushort4v;  // 4 bf16

__device__ __forceinline__ void splitf(float a, unsigned short& hi, unsigned short& lo) {
    unsigned ai = __float_as_uint(a);
    hi = (unsigned short)(ai >> 16);
    float r = a - __uint_as_float(ai & 0xffff0000u);
    lo = (unsigned short)(__float_as_uint(r) >> 16);
}

__device__ __forceinline__ unsigned short f2bf_rne(float f) {
    unsigned u = __float_as_uint(f);
    return (unsigned short)((u + 0x7fffu + ((u >> 16) & 1u)) >> 16);
}

__device__ __forceinline__ float bf2f(unsigned short u) {
    return __uint_as_float(((unsigned)u) << 16);
}

// ---------------- init: zero cursor/ovcnt (grid-stride) + dtype detect -----
__global__ void init_detect(const void* ei, int twoE, int* flag,
                            int* __restrict__ cursor, int* ovcnt, int N) {
    int i = blockIdx.x * 256 + threadIdx.x;
    int base = i * 4;
    if (base + 3 < N) {
        *(int4*)(cursor + base) = make_int4(0, 0, 0, 0);
    } else {
        for (int j = base; j < N && j < base + 4; ++j) cursor[j] = 0;
    }
    if (blockIdx.x == 0) {
        if (threadIdx.x == 0) *ovcnt = 0;
        __shared__ int ok;
        if (threadIdx.x == 0) ok = 1;
        __syncthreads();
        const int* p = (const int*)ei;
        for (int k = threadIdx.x; k < 512; k += 256) {
            long long pos = 1 + ((long long)k * (long long)(twoE - 2)) / 512;
            pos |= 1;  // odd int32 word of an int64 lane
            if (pos < twoE && p[pos] != 0) ok = 0;
        }
        __syncthreads();
        if (threadIdx.x == 0) *flag = ok;  // 1 => int64, 0 => int32
    }
}

// ---------------- prep: weight split + x -> bf16 ---------------------------
__global__ void prep_all(const float* __restrict__ Wl, const float* __restrict__ Wr,
                         const float* __restrict__ Wg,
                         unsigned short* __restrict__ WcH, unsigned short* __restrict__ WcL,
                         unsigned short* __restrict__ WgH, unsigned short* __restrict__ WgL,
                         const float* __restrict__ x, unsigned short* __restrict__ xbf,
                         size_t xElems) {
    size_t idx = (size_t)blockIdx.x * 256 + threadIdx.x;
    if (idx < 128 * 256) {
        int o = (int)(idx >> 8), k = (int)(idx & 255);
        float v = (k < 128) ? Wl[o * 128 + k] : Wr[o * 128 + (k - 128)];
        unsigned short h, l;
        splitf(v, h, l);
        WcH[idx] = h; WcL[idx] = l;
    } else if (idx < 128 * 256 + 64 * 128) {
        size_t j = idx - 128 * 256;
        unsigned short h, l;
        splitf(Wg[j], h, l);
        WgH[j] = h; WgL[j] = l;
    } else {
        size_t j = (idx - (128 * 256 + 64 * 128)) * 4;
        if (j < xElems) {
            float4 v = *(const float4*)(x + j);
            ushort4v o;
            o[0] = f2bf_rne(v.x);
            o[1] = f2bf_rne(v.y);
            o[2] = f2bf_rne(v.z);
            o[3] = f2bf_rne(v.w);
            *(ushort4v*)(xbf + j) = o;
        }
    }
}

// ---------------- adjacency build: one XCD-partitioned pass ----------------
// block b: dst-range (b&7) [r*N/8,(r+1)*N/8), edge-chunk stride (b>>3).
// cursor[d] ends as deg[d]; first FIX srcs in colf[d*FIX..]; rest -> ovlist.
__global__ void fill_fixed(const void* __restrict__ ei, const int* __restrict__ flag,
                           int* __restrict__ cursor, int* __restrict__ colf,
                           int2* __restrict__ ovlist, int* __restrict__ ovcnt,
                           int E, int N) {
    const int r = blockIdx.x & 7;
    const int slot = blockIdx.x >> 3;
    const int nslots = gridDim.x >> 3;
    const int lo = (int)((long long)r * N / 8);
    const int hi = (int)((long long)(r + 1) * N / 8);
    const int is64 = *flag;
    const int step = nslots * 256 * 4;

    for (int base = (slot * 256 + threadIdx.x) * 4; base < E; base += step) {
#pragma unroll
        for (int j = 0; j < 4; ++j) {
            int e = base + j;
            if (e >= E) break;
            int d, s;
            if (is64) {
                const long long* p = (const long long*)ei;
                d = (int)p[E + e];
                if (d < lo || d >= hi) continue;
                s = (int)p[e];
            } else {
                const int* p = (const int*)ei;
                d = p[E + e];
                if (d < lo || d >= hi) continue;
                s = p[e];
            }
            int pos = atomicAdd(&cursor[d], 1);
            if (pos < FIX) {
                colf[d * FIX + pos] = s;
            } else {
                int o = atomicAdd(ovcnt, 1);
                ovlist[o] = make_int2(d, s);
            }
        }
    }
}

// ---------------- gather mean: quarter-wave (16 lanes) per node ------------
__global__ void gather_mean(const int* __restrict__ degp, const int* __restrict__ colf,
                            const int2* __restrict__ ovlist, const int* __restrict__ ovcnt,
                            const unsigned short* __restrict__ xbf,
                            unsigned short* __restrict__ meanbf, int N) {
    int node = blockIdx.x * 16 + (threadIdx.x >> 4);
    if (node >= N) return;
    int sl = threadIdx.x & 15;
    int deg = degp[node];
    int nf = deg < FIX ? deg : FIX;
    float a0 = 0.f, a1 = 0.f, a2 = 0.f, a3 = 0.f, a4 = 0.f, a5 = 0.f, a6 = 0.f, a7 = 0.f;
    for (int e = 0; e < nf; ++e) {
        int s = colf[node * FIX + e];
        ushort8v v = *(const ushort8v*)(xbf + (size_t)s * DIN + sl * 8);
        a0 += bf2f(v[0]); a1 += bf2f(v[1]); a2 += bf2f(v[2]); a3 += bf2f(v[3]);
        a4 += bf2f(v[4]); a5 += bf2f(v[5]); a6 += bf2f(v[6]); a7 += bf2f(v[7]);
    }
    int oc = *ovcnt;
    for (int k = 0; k < oc; ++k) {       // normally oc == 0
        int2 pr = ovlist[k];
        if (pr.x == node) {
            ushort8v v = *(const ushort8v*)(xbf + (size_t)pr.y * DIN + sl * 8);
            a0 += bf2f(v[0]); a1 += bf2f(v[1]); a2 += bf2f(v[2]); a3 += bf2f(v[3]);
            a4 += bf2f(v[4]); a5 += bf2f(v[5]); a6 += bf2f(v[6]); a7 += bf2f(v[7]);
        }
    }
    float invd = (deg > 0) ? 1.0f / (float)deg : 0.f;
    ushort8v H;
    H[0] = f2bf_rne(a0 * invd); H[1] = f2bf_rne(a1 * invd);
    H[2] = f2bf_rne(a2 * invd); H[3] = f2bf_rne(a3 * invd);
    H[4] = f2bf_rne(a4 * invd); H[5] = f2bf_rne(a5 * invd);
    H[6] = f2bf_rne(a6 * invd); H[7] = f2bf_rne(a7 * invd);
    *(ushort8v*)(meanbf + (size_t)node * DIN + sl * 8) = H;
}

// ---------------- GEMM (swapped): h^T = Wcat*u^T; hw^T = dinv*(Wg*h^T) -----
__global__ __launch_bounds__(512, 4) void sage_gemm(
    const unsigned short* __restrict__ meanbf,
    const unsigned short* __restrict__ xbf,
    const unsigned short* __restrict__ WcH, const unsigned short* __restrict__ WcL,
    const unsigned short* __restrict__ WgH, const unsigned short* __restrict__ WgL,
    const float* __restrict__ bl, const int* __restrict__ degp,
    unsigned short* __restrict__ hwbf, int N, int ntiles)
{
    __shared__ unsigned short usH[2][32 * U_STR];
    __shared__ unsigned short hsH[2][32 * H_STR];
    const int tid = threadIdx.x;
    const int wave = tid >> 6;        // 0..7
    const int lane = tid & 63;
    const int lrow = lane & 15;       // A-row(feature) / B-col(node) / D-col(node)
    const int lk8  = (lane >> 4) << 3;
    const int qr   = (lane >> 4) << 2;

    // ---- GEMM1 weights: 16 features per wave, hi+lo (64 VGPRs)
    const int f1 = wave * 16 + lrow;
    short8v B1[8][2];
#pragma unroll
    for (int ks = 0; ks < 8; ++ks) {
        int kb = ks * 32 + lk8;
        B1[ks][0] = *(const short8v*)(WcH + f1 * 256 + kb);
        B1[ks][1] = *(const short8v*)(WcL + f1 * 256 + kb);
    }
    // ---- GEMM2 weights: feature-tile (wave&3), hi+lo (32 VGPRs)
    const int fw = (wave & 3) * 16;
    const int nw = (wave >> 2) * 16;
    const int f2 = fw + lrow;
    short8v B2[4][2];
#pragma unroll
    for (int ks = 0; ks < 4; ++ks) {
        int kb = ks * 32 + lk8;
        B2[ks][0] = *(const short8v*)(WgH + f2 * 128 + kb);
        B2[ks][1] = *(const short8v*)(WgL + f2 * 128 + kb);
    }
    const float4 bb = *(const float4*)(bl + wave * 16 + qr);

    auto stage = [&](int buf, int tile) {
        int nb = tile * NT;
        for (int idx = tid; idx < 32 * 32; idx += 512) {
            int n = idx >> 5;
            int c8 = (idx & 31) << 3;
            int node = nb + n;
            if (node >= N) node = N - 1;
            short8v v = (c8 < 128)
                            ? *(const short8v*)(meanbf + (size_t)node * DIN + c8)
                            : *(const short8v*)(xbf + (size_t)node * DIN + (c8 - 128));
            *(short8v*)(&usH[buf][n * U_STR + c8]) = v;
        }
    };

    int tile = blockIdx.x;
    if (tile >= ntiles) return;
    int buf = 0;
    stage(0, tile);
    __syncthreads();

    for (; tile < ntiles; tile += gridDim.x) {
        int nxt = tile + gridDim.x;
        if (nxt < ntiles) stage(buf ^ 1, nxt);   // overlap with this tile's MFMAs

        // ---- GEMM1: acc0 = W x u (nodes 0-15), acc1 = (nodes 16-31)
        float4v acc0 = {0.f, 0.f, 0.f, 0.f};
        float4v acc1 = {0.f, 0.f, 0.f, 0.f};
#pragma unroll
        for (int ks = 0; ks < 8; ++ks) {
            int kb = ks * 32 + lk8;
            short8v a0 = *(const short8v*)&usH[buf][lrow * U_STR + kb];
            short8v a1 = *(const short8v*)&usH[buf][(16 + lrow) * U_STR + kb];
            acc0 = __builtin_amdgcn_mfma_f32_16x16x32_bf16(B1[ks][0], a0, acc0, 0, 0, 0);
            acc0 = __builtin_amdgcn_mfma_f32_16x16x32_bf16(B1[ks][1], a0, acc0, 0, 0, 0);
            acc1 = __builtin_amdgcn_mfma_f32_16x16x32_bf16(B1[ks][0], a1, acc1, 0, 0, 0);
            acc1 = __builtin_amdgcn_mfma_f32_16x16x32_bf16(B1[ks][1], a1, acc1, 0, 0, 0);
        }
        __syncthreads();

        // ---- bias + ReLU -> bf16 h (packed 8B writes): h[node][feat]
        {
            ushort4v p;
            p[0] = f2bf_rne(fmaxf(acc0[0] + bb.x, 0.f));
            p[1] = f2bf_rne(fmaxf(acc0[1] + bb.y, 0.f));
            p[2] = f2bf_rne(fmaxf(acc0[2] + bb.z, 0.f));
            p[3] = f2bf_rne(fmaxf(acc0[3] + bb.w, 0.f));
            *(ushort4v*)&hsH[buf][lrow * H_STR + wave * 16 + qr] = p;
            p[0] = f2bf_rne(fmaxf(acc1[0] + bb.x, 0.f));
            p[1] = f2bf_rne(fmaxf(acc1[1] + bb.y, 0.f));
            p[2] = f2bf_rne(fmaxf(acc1[2] + bb.z, 0.f));
            p[3] = f2bf_rne(fmaxf(acc1[3] + bb.w, 0.f));
            *(ushort4v*)&hsH[buf][(16 + lrow) * H_STR + wave * 16 + qr] = p;
        }
        __syncthreads();

        // ---- GEMM2: acc2 = Wg x h  (feature-tile fw, node-tile nw)
        float4v acc2 = {0.f, 0.f, 0.f, 0.f};
#pragma unroll
        for (int ks = 0; ks < 4; ++ks) {
            int kb = ks * 32 + lk8;
            short8v a = *(const short8v*)&hsH[buf][(nw + lrow) * H_STR + kb];
            acc2 = __builtin_amdgcn_mfma_f32_16x16x32_bf16(B2[ks][0], a, acc2, 0, 0, 0);
            acc2 = __builtin_amdgcn_mfma_f32_16x16x32_bf16(B2[ks][1], a, acc2, 0, 0, 0);
        }

        // ---- write hw bf16 packed, PRE-SCALED by dinv[node]=rsqrt(deg+1)
        {
            int node = tile * NT + nw + lrow;
            if (node < N) {
                float dv = rsqrtf((float)degp[node] + 1.0f);
                ushort4v p;
                p[0] = f2bf_rne(dv * acc2[0]);
                p[1] = f2bf_rne(dv * acc2[1]);
                p[2] = f2bf_rne(dv * acc2[2]);
                p[3] = f2bf_rne(dv * acc2[3]);
                *(ushort4v*)(hwbf + (size_t)node * DOUT + fw + qr) = p;
            }
        }
        buf ^= 1;
    }
}

// ---------------- gather GCN + softmax: quarter-wave per node --------------
__global__ void gather_gcn_softmax(const int* __restrict__ degp, const int* __restrict__ colf,
                                   const int2* __restrict__ ovlist, const int* __restrict__ ovcnt,
                                   const unsigned short* __restrict__ hwbf,
                                   const float* __restrict__ bg,
                                   float* __restrict__ out, float* __restrict__ soft, int N) {
    int node = blockIdx.x * 16 + (threadIdx.x >> 4);
    if (node >= N) return;
    int sl = threadIdx.x & 15;
    int deg = degp[node];
    int nf = deg < FIX ? deg : FIX;

    // self term (pre-scaled) starts the accumulator
    ushort4v sv = *(const ushort4v*)(hwbf + (size_t)node * DOUT + sl * 4);
    float a0 = bf2f(sv[0]), a1 = bf2f(sv[1]), a2 = bf2f(sv[2]), a3 = bf2f(sv[3]);

    for (int e = 0; e < nf; ++e) {
        int s = colf[node * FIX + e];
        ushort4v v = *(const ushort4v*)(hwbf + (size_t)s * DOUT + sl * 4);
        a0 += bf2f(v[0]);
        a1 += bf2f(v[1]);
        a2 += bf2f(v[2]);
        a3 += bf2f(v[3]);
    }
    int oc = *ovcnt;
    for (int k = 0; k < oc; ++k) {       // normally oc == 0
        int2 pr = ovlist[k];
        if (pr.x == node) {
            ushort4v v = *(const ushort4v*)(hwbf + (size_t)pr.y * DOUT + sl * 4);
            a0 += bf2f(v[0]);
            a1 += bf2f(v[1]);
            a2 += bf2f(v[2]);
            a3 += bf2f(v[3]);
        }
    }

    float di = rsqrtf((float)deg + 1.0f);
    float4 bb = *(const float4*)(bg + sl * 4);
    float v0 = di * a0 + bb.x;
    float v1 = di * a1 + bb.y;
    float v2 = di * a2 + bb.z;
    float v3 = di * a3 + bb.w;

    // softmax over 64 cols held by 16 lanes x 4
    float m = fmaxf(fmaxf(v0, v1), fmaxf(v2, v3));
#pragma unroll
    for (int mask = 8; mask; mask >>= 1) m = fmaxf(m, __shfl_xor(m, mask, 64));
    float e0 = __expf(v0 - m), e1 = __expf(v1 - m), e2 = __expf(v2 - m), e3 = __expf(v3 - m);
    float s = e0 + e1 + e2 + e3;
#pragma unroll
    for (int mask = 8; mask; mask >>= 1) s += __shfl_xor(s, mask, 64);
    float inv = 1.0f / s;
    *(float4*)(out + (size_t)node * DOUT + sl * 4) = make_float4(v0, v1, v2, v3);
    *(float4*)(soft + (size_t)node * DOUT + sl * 4) =
        make_float4(e0 * inv, e1 * inv, e2 * inv, e3 * inv);
}

// ---------------------------------------------------------------------------
extern "C" void kernel_launch(void* const* d_in, const int* in_sizes, int n_in,
                              void* d_out, int out_size, void* d_ws, size_t ws_size,
                              hipStream_t stream) {
    const float* x  = (const float*)d_in[0];
    const void*  ei = d_in[1];
    const float* Wl = (const float*)d_in[2];
    const float* bl = (const float*)d_in[3];
    const float* Wr = (const float*)d_in[4];
    const float* Wg = (const float*)d_in[5];
    const float* bg = (const float*)d_in[6];
    const int N = in_sizes[0] / DIN;
    const int E = in_sizes[1] / 2;
    float* out = (float*)d_out;

    char* ws = (char*)d_ws;
    size_t off = 0;
    auto alloc = [&](size_t bytes) {
        void* p = ws + off;
        off += (bytes + 255) / 256 * 256;
        return p;
    };
    int*   flag    = (int*)alloc(4);
    int*   ovcnt   = (int*)alloc(4);
    int*   cursor  = (int*)alloc((size_t)N * 4);          // becomes deg
    int*   colf    = (int*)alloc((size_t)N * FIX * 4);    // fixed adjacency
    int2*  ovlist  = (int2*)alloc((size_t)E * 8);         // overflow pairs
    unsigned short* WcH = (unsigned short*)alloc(128 * 256 * 2);
    unsigned short* WcL = (unsigned short*)alloc(128 * 256 * 2);
    unsigned short* WgH = (unsigned short*)alloc(64 * 128 * 2);
    unsigned short* WgL = (unsigned short*)alloc(64 * 128 * 2);
    unsigned short* xbf    = (unsigned short*)alloc((size_t)N * DIN * 2);
    unsigned short* meanbf = (unsigned short*)alloc((size_t)N * DIN * 2);
    unsigned short* hwbf   = (unsigned short*)alloc((size_t)N * DOUT * 2);
    (void)ws_size; (void)n_in; (void)out_size;

    float* soft = out + (size_t)N * DOUT;

    const int ntiles = (N + NT - 1) / NT;

    init_detect<<<(N / 4 + 255) / 256 + 1, 256, 0, stream>>>(ei, 2 * E, flag, cursor, ovcnt, N);
    {
        size_t xElems = (size_t)N * DIN;
        size_t total = 128 * 256 + 64 * 128 + (xElems + 3) / 4;
        prep_all<<<(int)((total + 255) / 256), 256, 0, stream>>>(
            Wl, Wr, Wg, WcH, WcL, WgH, WgL, x, xbf, xElems);
    }
    fill_fixed<<<8 * 128, 256, 0, stream>>>(ei, flag, cursor, colf, ovlist, ovcnt, E, N);
    gather_mean<<<(N + 15) / 16, 256, 0, stream>>>(cursor, colf, ovlist, ovcnt, xbf, meanbf, N);
    sage_gemm<<<512, 512, 0, stream>>>(meanbf, xbf, WcH, WcL, WgH, WgL, bl, cursor, hwbf, N, ntiles);
    gather_gcn_softmax<<<(N + 15) / 16, 256, 0, stream>>>(cursor, colf, ovlist, ovcnt, hwbf, bg, out, soft, N);
}

// Round 13
// 129.092 us; speedup vs baseline: 1.8483x; 1.1724x over previous
//
#include <hip/hip_runtime.h>
#include <math.h>

// GraphSAGE (mean) + GCN + softmax. Activations RNE-bf16, weights split
// hi/lo bf16, f32 accumulate. MFMA operand-swapped (A=weights, B=activations).
// hw stored pre-scaled by dinv -> GCN gather is a pure sum.
// Fixed-stride adjacency (24 slots/node) + overflow list, one XCD-partitioned
// build pass. Gathers: col entries prefetched to registers + shfl broadcast,
// row loads pipelined 4-deep.
// N=100000, E=625000, D_IN=D_H=128, D_OUT=64 (derived from in_sizes).

#define DIN 128
#define DH  128
#define DOUT 64
#define NT  32      // nodes per GEMM tile
#define FIX 24      // fixed adjacency slots per node
#define U_STR 264   // 256 + 8 pad (ushort)
#define H_STR 136   // 128 + 8 pad (ushort)

typedef __attribute__((ext_vector_type(8))) short short8v;            // 8 bf16
typedef __attribute__((ext_vector_type(4))) float float4v;            // MFMA acc
typedef __attribute__((ext_vector_type(8))) unsigned short ushort8v;  // 8 bf16
typedef __attribute__((ext_vector_type(4))) unsigned short ushort4v;  // 4 bf16

__device__ __forceinline__ void splitf(float a, unsigned short& hi, unsigned short& lo) {
    unsigned ai = __float_as_uint(a);
    hi = (unsigned short)(ai >> 16);
    float r = a - __uint_as_float(ai & 0xffff0000u);
    lo = (unsigned short)(__float_as_uint(r) >> 16);
}

__device__ __forceinline__ unsigned short f2bf_rne(float f) {
    unsigned u = __float_as_uint(f);
    return (unsigned short)((u + 0x7fffu + ((u >> 16) & 1u)) >> 16);
}

__device__ __forceinline__ float bf2f(unsigned short u) {
    return __uint_as_float(((unsigned)u) << 16);
}

// ---------------- prep + init fused ---------------------------------------
// blocks [0, PB): weight split + x->bf16.  block PB: zero-pad tail + detect.
// cursor zeroing folded in as extra range.
__global__ void prep_init(const float* __restrict__ Wl, const float* __restrict__ Wr,
                          const float* __restrict__ Wg,
                          unsigned short* __restrict__ WcH, unsigned short* __restrict__ WcL,
                          unsigned short* __restrict__ WgH, unsigned short* __restrict__ WgL,
                          const float* __restrict__ x, unsigned short* __restrict__ xbf,
                          size_t xElems,
                          const void* ei, int twoE, int* flag,
                          int* __restrict__ cursor, int* ovcnt, int N) {
    size_t idx = (size_t)blockIdx.x * 256 + threadIdx.x;
    const size_t W1 = 128 * 256;
    const size_t W2 = W1 + 64 * 128;
    const size_t X2 = W2 + (xElems >> 2);
    const size_t C2 = X2 + (size_t)((N + 3) >> 2);
    if (idx < W1) {
        int o = (int)(idx >> 8), k = (int)(idx & 255);
        float v = (k < 128) ? Wl[o * 128 + k] : Wr[o * 128 + (k - 128)];
        unsigned short h, l;
        splitf(v, h, l);
        WcH[idx] = h; WcL[idx] = l;
    } else if (idx < W2) {
        size_t j = idx - W1;
        unsigned short h, l;
        splitf(Wg[j], h, l);
        WgH[j] = h; WgL[j] = l;
    } else if (idx < X2) {
        size_t j = (idx - W2) * 4;
        float4 v = *(const float4*)(x + j);
        ushort4v o;
        o[0] = f2bf_rne(v.x);
        o[1] = f2bf_rne(v.y);
        o[2] = f2bf_rne(v.z);
        o[3] = f2bf_rne(v.w);
        *(ushort4v*)(xbf + j) = o;
    } else if (idx < C2) {
        size_t b = (idx - X2) * 4;
        if (b + 3 < (size_t)N) {
            *(int4*)(cursor + b) = make_int4(0, 0, 0, 0);
        } else {
            for (size_t j = b; j < (size_t)N && j < b + 4; ++j) cursor[j] = 0;
        }
    } else {
        // one trailing block: dtype detect + ovcnt
        if (threadIdx.x == 0) *ovcnt = 0;
        __shared__ int ok;
        if (threadIdx.x == 0) ok = 1;
        __syncthreads();
        const int* p = (const int*)ei;
        for (int k = threadIdx.x; k < 512; k += 256) {
            long long pos = 1 + ((long long)k * (long long)(twoE - 2)) / 512;
            pos |= 1;
            if (pos < twoE && p[pos] != 0) ok = 0;
        }
        __syncthreads();
        if (threadIdx.x == 0) *flag = ok;  // 1 => int64, 0 => int32
    }
}

// ---------------- adjacency build: one XCD-partitioned pass ----------------
__global__ void fill_fixed(const void* __restrict__ ei, const int* __restrict__ flag,
                           int* __restrict__ cursor, int* __restrict__ colf,
                           int2* __restrict__ ovlist, int* __restrict__ ovcnt,
                           int E, int N) {
    const int r = blockIdx.x & 7;
    const int slot = blockIdx.x >> 3;
    const int nslots = gridDim.x >> 3;
    const int lo = (int)((long long)r * N / 8);
    const int hi = (int)((long long)(r + 1) * N / 8);
    const int is64 = *flag;
    const int step = nslots * 256 * 4;

    for (int base = (slot * 256 + threadIdx.x) * 4; base < E; base += step) {
#pragma unroll
        for (int j = 0; j < 4; ++j) {
            int e = base + j;
            if (e >= E) break;
            int d, s;
            if (is64) {
                const long long* p = (const long long*)ei;
                d = (int)p[E + e];
                if (d < lo || d >= hi) continue;
                s = (int)p[e];
            } else {
                const int* p = (const int*)ei;
                d = p[E + e];
                if (d < lo || d >= hi) continue;
                s = p[e];
            }
            int pos = atomicAdd(&cursor[d], 1);
            if (pos < FIX) {
                colf[d * FIX + pos] = s;
            } else {
                int o = atomicAdd(ovcnt, 1);
                ovlist[o] = make_int2(d, s);
            }
        }
    }
}

// ---------------- gather mean: quarter-wave per node, col-prefetch ---------
__global__ void gather_mean(const int* __restrict__ degp, const int* __restrict__ colf,
                            const int2* __restrict__ ovlist, const int* __restrict__ ovcnt,
                            const unsigned short* __restrict__ xbf,
                            unsigned short* __restrict__ meanbf, int N) {
    int node = blockIdx.x * 16 + (threadIdx.x >> 4);
    if (node >= N) return;
    int lane = threadIdx.x & 63;
    int sl = lane & 15;
    int gb = lane & 48;   // quarter-group base lane
    int deg = degp[node];
    int nf = deg < FIX ? deg : FIX;

    // prefetch col entries: lane sl holds entry sl (c0) and 16+sl (c1, sl<8)
    int c0 = colf[node * FIX + sl];
    int c1 = (sl < 8) ? colf[node * FIX + 16 + sl] : 0;
    auto getcol = [&](int e) {
        return (e < 16) ? __shfl(c0, gb + e, 64) : __shfl(c1, gb + e - 16, 64);
    };

    float a0 = 0.f, a1 = 0.f, a2 = 0.f, a3 = 0.f, a4 = 0.f, a5 = 0.f, a6 = 0.f, a7 = 0.f;
    int e = 0;
    for (; e + 3 < nf; e += 4) {   // 4 row loads in flight
        int s0 = getcol(e), s1 = getcol(e + 1), s2 = getcol(e + 2), s3 = getcol(e + 3);
        ushort8v v0 = *(const ushort8v*)(xbf + (size_t)s0 * DIN + sl * 8);
        ushort8v v1 = *(const ushort8v*)(xbf + (size_t)s1 * DIN + sl * 8);
        ushort8v v2 = *(const ushort8v*)(xbf + (size_t)s2 * DIN + sl * 8);
        ushort8v v3 = *(const ushort8v*)(xbf + (size_t)s3 * DIN + sl * 8);
        a0 += bf2f(v0[0]) + bf2f(v1[0]) + bf2f(v2[0]) + bf2f(v3[0]);
        a1 += bf2f(v0[1]) + bf2f(v1[1]) + bf2f(v2[1]) + bf2f(v3[1]);
        a2 += bf2f(v0[2]) + bf2f(v1[2]) + bf2f(v2[2]) + bf2f(v3[2]);
        a3 += bf2f(v0[3]) + bf2f(v1[3]) + bf2f(v2[3]) + bf2f(v3[3]);
        a4 += bf2f(v0[4]) + bf2f(v1[4]) + bf2f(v2[4]) + bf2f(v3[4]);
        a5 += bf2f(v0[5]) + bf2f(v1[5]) + bf2f(v2[5]) + bf2f(v3[5]);
        a6 += bf2f(v0[6]) + bf2f(v1[6]) + bf2f(v2[6]) + bf2f(v3[6]);
        a7 += bf2f(v0[7]) + bf2f(v1[7]) + bf2f(v2[7]) + bf2f(v3[7]);
    }
    for (; e + 1 < nf; e += 2) {
        int s0 = getcol(e), s1 = getcol(e + 1);
        ushort8v v0 = *(const ushort8v*)(xbf + (size_t)s0 * DIN + sl * 8);
        ushort8v v1 = *(const ushort8v*)(xbf + (size_t)s1 * DIN + sl * 8);
        a0 += bf2f(v0[0]) + bf2f(v1[0]);
        a1 += bf2f(v0[1]) + bf2f(v1[1]);
        a2 += bf2f(v0[2]) + bf2f(v1[2]);
        a3 += bf2f(v0[3]) + bf2f(v1[3]);
        a4 += bf2f(v0[4]) + bf2f(v1[4]);
        a5 += bf2f(v0[5]) + bf2f(v1[5]);
        a6 += bf2f(v0[6]) + bf2f(v1[6]);
        a7 += bf2f(v0[7]) + bf2f(v1[7]);
    }
    if (e < nf) {
        int s0 = getcol(e);
        ushort8v v0 = *(const ushort8v*)(xbf + (size_t)s0 * DIN + sl * 8);
        a0 += bf2f(v0[0]); a1 += bf2f(v0[1]); a2 += bf2f(v0[2]); a3 += bf2f(v0[3]);
        a4 += bf2f(v0[4]); a5 += bf2f(v0[5]); a6 += bf2f(v0[6]); a7 += bf2f(v0[7]);
    }
    int oc = *ovcnt;
    for (int k = 0; k < oc; ++k) {       // normally oc == 0
        int2 pr = ovlist[k];
        if (pr.x == node) {
            ushort8v v = *(const ushort8v*)(xbf + (size_t)pr.y * DIN + sl * 8);
            a0 += bf2f(v[0]); a1 += bf2f(v[1]); a2 += bf2f(v[2]); a3 += bf2f(v[3]);
            a4 += bf2f(v[4]); a5 += bf2f(v[5]); a6 += bf2f(v[6]); a7 += bf2f(v[7]);
        }
    }
    float invd = (deg > 0) ? 1.0f / (float)deg : 0.f;
    ushort8v H;
    H[0] = f2bf_rne(a0 * invd); H[1] = f2bf_rne(a1 * invd);
    H[2] = f2bf_rne(a2 * invd); H[3] = f2bf_rne(a3 * invd);
    H[4] = f2bf_rne(a4 * invd); H[5] = f2bf_rne(a5 * invd);
    H[6] = f2bf_rne(a6 * invd); H[7] = f2bf_rne(a7 * invd);
    *(ushort8v*)(meanbf + (size_t)node * DIN + sl * 8) = H;
}

// ---------------- GEMM (swapped): h^T = Wcat*u^T; hw^T = dinv*(Wg*h^T) -----
__global__ __launch_bounds__(512, 4) void sage_gemm(
    const unsigned short* __restrict__ meanbf,
    const unsigned short* __restrict__ xbf,
    const unsigned short* __restrict__ WcH, const unsigned short* __restrict__ WcL,
    const unsigned short* __restrict__ WgH, const unsigned short* __restrict__ WgL,
    const float* __restrict__ bl, const int* __restrict__ degp,
    unsigned short* __restrict__ hwbf, int N, int ntiles)
{
    __shared__ unsigned short usH[2][32 * U_STR];
    __shared__ unsigned short hsH[2][32 * H_STR];
    const int tid = threadIdx.x;
    const int wave = tid >> 6;        // 0..7
    const int lane = tid & 63;
    const int lrow = lane & 15;       // A-row(feature) / B-col(node) / D-col(node)
    const int lk8  = (lane >> 4) << 3;
    const int qr   = (lane >> 4) << 2;

    // ---- GEMM1 weights: 16 features per wave, hi+lo (64 VGPRs)
    const int f1 = wave * 16 + lrow;
    short8v B1[8][2];
#pragma unroll
    for (int ks = 0; ks < 8; ++ks) {
        int kb = ks * 32 + lk8;
        B1[ks][0] = *(const short8v*)(WcH + f1 * 256 + kb);
        B1[ks][1] = *(const short8v*)(WcL + f1 * 256 + kb);
    }
    // ---- GEMM2 weights: feature-tile (wave&3), hi+lo (32 VGPRs)
    const int fw = (wave & 3) * 16;
    const int nw = (wave >> 2) * 16;
    const int f2 = fw + lrow;
    short8v B2[4][2];
#pragma unroll
    for (int ks = 0; ks < 4; ++ks) {
        int kb = ks * 32 + lk8;
        B2[ks][0] = *(const short8v*)(WgH + f2 * 128 + kb);
        B2[ks][1] = *(const short8v*)(WgL + f2 * 128 + kb);
    }
    const float4 bb = *(const float4*)(bl + wave * 16 + qr);

    auto stage = [&](int buf, int tile) {
        int nb = tile * NT;
        for (int idx = tid; idx < 32 * 32; idx += 512) {
            int n = idx >> 5;
            int c8 = (idx & 31) << 3;
            int node = nb + n;
            if (node >= N) node = N - 1;
            short8v v = (c8 < 128)
                            ? *(const short8v*)(meanbf + (size_t)node * DIN + c8)
                            : *(const short8v*)(xbf + (size_t)node * DIN + (c8 - 128));
            *(short8v*)(&usH[buf][n * U_STR + c8]) = v;
        }
    };

    int tile = blockIdx.x;
    if (tile >= ntiles) return;
    int buf = 0;
    stage(0, tile);
    __syncthreads();

    for (; tile < ntiles; tile += gridDim.x) {
        int nxt = tile + gridDim.x;
        if (nxt < ntiles) stage(buf ^ 1, nxt);   // overlap with this tile's MFMAs

        // ---- GEMM1: acc0 = W x u (nodes 0-15), acc1 = (nodes 16-31)
        float4v acc0 = {0.f, 0.f, 0.f, 0.f};
        float4v acc1 = {0.f, 0.f, 0.f, 0.f};
#pragma unroll
        for (int ks = 0; ks < 8; ++ks) {
            int kb = ks * 32 + lk8;
            short8v a0 = *(const short8v*)&usH[buf][lrow * U_STR + kb];
            short8v a1 = *(const short8v*)&usH[buf][(16 + lrow) * U_STR + kb];
            acc0 = __builtin_amdgcn_mfma_f32_16x16x32_bf16(B1[ks][0], a0, acc0, 0, 0, 0);
            acc0 = __builtin_amdgcn_mfma_f32_16x16x32_bf16(B1[ks][1], a0, acc0, 0, 0, 0);
            acc1 = __builtin_amdgcn_mfma_f32_16x16x32_bf16(B1[ks][0], a1, acc1, 0, 0, 0);
            acc1 = __builtin_amdgcn_mfma_f32_16x16x32_bf16(B1[ks][1], a1, acc1, 0, 0, 0);
        }
        __syncthreads();

        // ---- bias + ReLU -> bf16 h (packed 8B writes): h[node][feat]
        {
            ushort4v p;
            p[0] = f2bf_rne(fmaxf(acc0[0] + bb.x, 0.f));
            p[1] = f2bf_rne(fmaxf(acc0[1] + bb.y, 0.f));
            p[2] = f2bf_rne(fmaxf(acc0[2] + bb.z, 0.f));
            p[3] = f2bf_rne(fmaxf(acc0[3] + bb.w, 0.f));
            *(ushort4v*)&hsH[buf][lrow * H_STR + wave * 16 + qr] = p;
            p[0] = f2bf_rne(fmaxf(acc1[0] + bb.x, 0.f));
            p[1] = f2bf_rne(fmaxf(acc1[1] + bb.y, 0.f));
            p[2] = f2bf_rne(fmaxf(acc1[2] + bb.z, 0.f));
            p[3] = f2bf_rne(fmaxf(acc1[3] + bb.w, 0.f));
            *(ushort4v*)&hsH[buf][(16 + lrow) * H_STR + wave * 16 + qr] = p;
        }
        __syncthreads();

        // ---- GEMM2: acc2 = Wg x h  (feature-tile fw, node-tile nw)
        float4v acc2 = {0.f, 0.f, 0.f, 0.f};
#pragma unroll
        for (int ks = 0; ks < 4; ++ks) {
            int kb = ks * 32 + lk8;
            short8v a = *(const short8v*)&hsH[buf][(nw + lrow) * H_STR + kb];
            acc2 = __builtin_amdgcn_mfma_f32_16x16x32_bf16(B2[ks][0], a, acc2, 0, 0, 0);
            acc2 = __builtin_amdgcn_mfma_f32_16x16x32_bf16(B2[ks][1], a, acc2, 0, 0, 0);
        }

        // ---- write hw bf16 packed, PRE-SCALED by dinv[node]=rsqrt(deg+1)
        {
            int node = tile * NT + nw + lrow;
            if (node < N) {
                float dv = rsqrtf((float)degp[node] + 1.0f);
                ushort4v p;
                p[0] = f2bf_rne(dv * acc2[0]);
                p[1] = f2bf_rne(dv * acc2[1]);
                p[2] = f2bf_rne(dv * acc2[2]);
                p[3] = f2bf_rne(dv * acc2[3]);
                *(ushort4v*)(hwbf + (size_t)node * DOUT + fw + qr) = p;
            }
        }
        buf ^= 1;
    }
}

// ---------------- gather GCN + softmax: quarter-wave per node --------------
__global__ void gather_gcn_softmax(const int* __restrict__ degp, const int* __restrict__ colf,
                                   const int2* __restrict__ ovlist, const int* __restrict__ ovcnt,
                                   const unsigned short* __restrict__ hwbf,
                                   const float* __restrict__ bg,
                                   float* __restrict__ out, float* __restrict__ soft, int N) {
    int node = blockIdx.x * 16 + (threadIdx.x >> 4);
    if (node >= N) return;
    int lane = threadIdx.x & 63;
    int sl = lane & 15;
    int gb = lane & 48;
    int deg = degp[node];
    int nf = deg < FIX ? deg : FIX;

    int c0 = colf[node * FIX + sl];
    int c1 = (sl < 8) ? colf[node * FIX + 16 + sl] : 0;
    auto getcol = [&](int e) {
        return (e < 16) ? __shfl(c0, gb + e, 64) : __shfl(c1, gb + e - 16, 64);
    };

    // self term (pre-scaled) starts the accumulator
    ushort4v sv = *(const ushort4v*)(hwbf + (size_t)node * DOUT + sl * 4);
    float a0 = bf2f(sv[0]), a1 = bf2f(sv[1]), a2 = bf2f(sv[2]), a3 = bf2f(sv[3]);

    int e = 0;
    for (; e + 3 < nf; e += 4) {   // 4 row loads in flight
        int s0 = getcol(e), s1 = getcol(e + 1), s2 = getcol(e + 2), s3 = getcol(e + 3);
        ushort4v v0 = *(const ushort4v*)(hwbf + (size_t)s0 * DOUT + sl * 4);
        ushort4v v1 = *(const ushort4v*)(hwbf + (size_t)s1 * DOUT + sl * 4);
        ushort4v v2 = *(const ushort4v*)(hwbf + (size_t)s2 * DOUT + sl * 4);
        ushort4v v3 = *(const ushort4v*)(hwbf + (size_t)s3 * DOUT + sl * 4);
        a0 += bf2f(v0[0]) + bf2f(v1[0]) + bf2f(v2[0]) + bf2f(v3[0]);
        a1 += bf2f(v0[1]) + bf2f(v1[1]) + bf2f(v2[1]) + bf2f(v3[1]);
        a2 += bf2f(v0[2]) + bf2f(v1[2]) + bf2f(v2[2]) + bf2f(v3[2]);
        a3 += bf2f(v0[3]) + bf2f(v1[3]) + bf2f(v2[3]) + bf2f(v3[3]);
    }
    for (; e + 1 < nf; e += 2) {
        int s0 = getcol(e), s1 = getcol(e + 1);
        ushort4v v0 = *(const ushort4v*)(hwbf + (size_t)s0 * DOUT + sl * 4);
        ushort4v v1 = *(const ushort4v*)(hwbf + (size_t)s1 * DOUT + sl * 4);
        a0 += bf2f(v0[0]) + bf2f(v1[0]);
        a1 += bf2f(v0[1]) + bf2f(v1[1]);
        a2 += bf2f(v0[2]) + bf2f(v1[2]);
        a3 += bf2f(v0[3]) + bf2f(v1[3]);
    }
    if (e < nf) {
        int s0 = getcol(e);
        ushort4v v0 = *(const ushort4v*)(hwbf + (size_t)s0 * DOUT + sl * 4);
        a0 += bf2f(v0[0]);
        a1 += bf2f(v0[1]);
        a2 += bf2f(v0[2]);
        a3 += bf2f(v0[3]);
    }
    int oc = *ovcnt;
    for (int k = 0; k < oc; ++k) {       // normally oc == 0
        int2 pr = ovlist[k];
        if (pr.x == node) {
            ushort4v v = *(const ushort4v*)(hwbf + (size_t)pr.y * DOUT + sl * 4);
            a0 += bf2f(v[0]);
            a1 += bf2f(v[1]);
            a2 += bf2f(v[2]);
            a3 += bf2f(v[3]);
        }
    }

    float di = rsqrtf((float)deg + 1.0f);
    float4 bb = *(const float4*)(bg + sl * 4);
    float v0 = di * a0 + bb.x;
    float v1 = di * a1 + bb.y;
    float v2 = di * a2 + bb.z;
    float v3 = di * a3 + bb.w;

    // softmax over 64 cols held by 16 lanes x 4
    float m = fmaxf(fmaxf(v0, v1), fmaxf(v2, v3));
#pragma unroll
    for (int mask = 8; mask; mask >>= 1) m = fmaxf(m, __shfl_xor(m, mask, 64));
    float e0 = __expf(v0 - m), e1 = __expf(v1 - m), e2 = __expf(v2 - m), e3 = __expf(v3 - m);
    float s = e0 + e1 + e2 + e3;
#pragma unroll
    for (int mask = 8; mask; mask >>= 1) s += __shfl_xor(s, mask, 64);
    float inv = 1.0f / s;
    *(float4*)(out + (size_t)node * DOUT + sl * 4) = make_float4(v0, v1, v2, v3);
    *(float4*)(soft + (size_t)node * DOUT + sl * 4) =
        make_float4(e0 * inv, e1 * inv, e2 * inv, e3 * inv);
}

// ---------------------------------------------------------------------------
extern "C" void kernel_launch(void* const* d_in, const int* in_sizes, int n_in,
                              void* d_out, int out_size, void* d_ws, size_t ws_size,
                              hipStream_t stream) {
    const float* x  = (const float*)d_in[0];
    const void*  ei = d_in[1];
    const float* Wl = (const float*)d_in[2];
    const float* bl = (const float*)d_in[3];
    const float* Wr = (const float*)d_in[4];
    const float* Wg = (const float*)d_in[5];
    const float* bg = (const float*)d_in[6];
    const int N = in_sizes[0] / DIN;
    const int E = in_sizes[1] / 2;
    float* out = (float*)d_out;

    char* ws = (char*)d_ws;
    size_t off = 0;
    auto alloc = [&](size_t bytes) {
        void* p = ws + off;
        off += (bytes + 255) / 256 * 256;
        return p;
    };
    int*   flag    = (int*)alloc(4);
    int*   ovcnt   = (int*)alloc(4);
    int*   cursor  = (int*)alloc((size_t)N * 4);          // becomes deg
    int*   colf    = (int*)alloc((size_t)N * FIX * 4);    // fixed adjacency
    int2*  ovlist  = (int2*)alloc((size_t)E * 8);         // overflow pairs
    unsigned short* WcH = (unsigned short*)alloc(128 * 256 * 2);
    unsigned short* WcL = (unsigned short*)alloc(128 * 256 * 2);
    unsigned short* WgH = (unsigned short*)alloc(64 * 128 * 2);
    unsigned short* WgL = (unsigned short*)alloc(64 * 128 * 2);
    unsigned short* xbf    = (unsigned short*)alloc((size_t)N * DIN * 2);
    unsigned short* meanbf = (unsigned short*)alloc((size_t)N * DIN * 2);
    unsigned short* hwbf   = (unsigned short*)alloc((size_t)N * DOUT * 2);
    (void)ws_size; (void)n_in; (void)out_size;

    float* soft = out + (size_t)N * DOUT;

    const int ntiles = (N + NT - 1) / NT;

    {
        size_t xElems = (size_t)N * DIN;
        size_t total = 128 * 256 + 64 * 128 + (xElems >> 2) + (size_t)((N + 3) >> 2);
        int blocks = (int)((total + 255) / 256) + 1;   // +1 detect block
        prep_init<<<blocks, 256, 0, stream>>>(Wl, Wr, Wg, WcH, WcL, WgH, WgL,
                                              x, xbf, xElems, ei, 2 * E, flag,
                                              cursor, ovcnt, N);
    }
    fill_fixed<<<8 * 128, 256, 0, stream>>>(ei, flag, cursor, colf, ovlist, ovcnt, E, N);
    gather_mean<<<(N + 15) / 16, 256, 0, stream>>>(cursor, colf, ovlist, ovcnt, xbf, meanbf, N);
    sage_gemm<<<512, 512, 0, stream>>>(meanbf, xbf, WcH, WcL, WgH, WgL, bl, cursor, hwbf, N, ntiles);
    gather_gcn_softmax<<<(N + 15) / 16, 256, 0, stream>>>(cursor, colf, ovlist, ovcnt, hwbf, bg, out, soft, N);
}